// Round 1
// baseline (993.789 us; speedup 1.0000x reference)
//
#include <hip/hip_runtime.h>
#include <math.h>

#define N_NODES 50000
#define N_EDGES 800000
#define IN_DIM  512
#define HID     128
#define OUT_DIM 64
#define EPS     0.3f

__device__ __forceinline__ float fast_tanh(float x) {
    // tanh(x) = 1 - 2/(exp(2x)+1); saturates correctly at +/-inf
    return 1.0f - 2.0f / (__expf(2.0f * x) + 1.0f);
}

// ---------------- CSR build ----------------

__global__ void hist_k(const int* __restrict__ dst, int* __restrict__ deg) {
    int e = blockIdx.x * blockDim.x + threadIdx.x;
    if (e < N_EDGES) atomicAdd(&deg[dst[e]], 1);
}

__global__ void scan_k(const int* __restrict__ deg, int* __restrict__ rowptr,
                       int* __restrict__ cursor) {
    __shared__ int buf[1024];
    __shared__ int carry;
    if (threadIdx.x == 0) carry = 0;
    __syncthreads();
    for (int base = 0; base < N_NODES; base += 1024) {
        int i = base + (int)threadIdx.x;
        int v = (i < N_NODES) ? deg[i] : 0;
        buf[threadIdx.x] = v;
        __syncthreads();
        for (int off = 1; off < 1024; off <<= 1) {
            int t = 0;
            if ((int)threadIdx.x >= off) t = buf[threadIdx.x - off];
            __syncthreads();
            if ((int)threadIdx.x >= off) buf[threadIdx.x] += t;
            __syncthreads();
        }
        int excl = buf[threadIdx.x] - v + carry;  // exclusive prefix + running carry
        if (i < N_NODES) { rowptr[i] = excl; cursor[i] = excl; }
        int tot = buf[1023];
        __syncthreads();
        if (threadIdx.x == 0) carry += tot;
        __syncthreads();
    }
    if (threadIdx.x == 0) rowptr[N_NODES] = carry;
}

__global__ void fill_k(const int* __restrict__ src, const int* __restrict__ dst,
                       const int* __restrict__ yn, int* __restrict__ cursor,
                       int* __restrict__ csr) {
    int e = blockIdx.x * blockDim.x + threadIdx.x;
    if (e >= N_EDGES) return;
    int pos = atomicAdd(&cursor[dst[e]], 1);
    csr[pos] = src[e] | (yn[e] << 31);   // src < 2^17, yn packed in sign bit
}

// ---------------- t1: x = relu(h @ t1_w^T + b), 50000x512 -> 50000x128 ----------------

__launch_bounds__(256)
__global__ void t1_k(const float* __restrict__ h, const float* __restrict__ w,
                     const float* __restrict__ bias, float* __restrict__ out) {
    __shared__ float As[64][36];    // 64 nodes x 32 k (+4 pad, float4-aligned)
    __shared__ float Bs[128][36];   // 128 outs x 32 k
    int tid = threadIdx.x;
    int n0  = blockIdx.x * 64;
    int tn = tid >> 4, to = tid & 15;
    float acc[4][8];
#pragma unroll
    for (int i = 0; i < 4; i++)
#pragma unroll
        for (int j = 0; j < 8; j++) acc[i][j] = 0.0f;

    for (int k0 = 0; k0 < IN_DIM; k0 += 32) {
        // A tile: 64x32 floats = 512 float4, 2 per thread
#pragma unroll
        for (int j = 0; j < 2; j++) {
            int f4 = tid + j * 256;
            int r = f4 >> 3, c = (f4 & 7) * 4;
            int gr = n0 + r;
            float4 v = make_float4(0.f, 0.f, 0.f, 0.f);
            if (gr < N_NODES) v = *(const float4*)&h[gr * IN_DIM + k0 + c];
            *(float4*)&As[r][c] = v;
        }
        // B tile: 128x32 floats = 1024 float4, 4 per thread
#pragma unroll
        for (int j = 0; j < 4; j++) {
            int f4 = tid + j * 256;
            int r = f4 >> 3, c = (f4 & 7) * 4;
            *(float4*)&Bs[r][c] = *(const float4*)&w[r * IN_DIM + k0 + c];
        }
        __syncthreads();
#pragma unroll
        for (int k = 0; k < 32; k += 4) {
            float4 av[4], bv[8];
#pragma unroll
            for (int i = 0; i < 4; i++) av[i] = *(const float4*)&As[tn + 16 * i][k];
#pragma unroll
            for (int j = 0; j < 8; j++) bv[j] = *(const float4*)&Bs[to + 16 * j][k];
#pragma unroll
            for (int i = 0; i < 4; i++)
#pragma unroll
                for (int j = 0; j < 8; j++) {
                    acc[i][j] += av[i].x * bv[j].x;
                    acc[i][j] += av[i].y * bv[j].y;
                    acc[i][j] += av[i].z * bv[j].z;
                    acc[i][j] += av[i].w * bv[j].w;
                }
        }
        __syncthreads();
    }
#pragma unroll
    for (int j = 0; j < 8; j++) {
        int o = to + 16 * j;
        float b = bias[o];
#pragma unroll
        for (int i = 0; i < 4; i++) {
            int r = n0 + tn + 16 * i;
            if (r < N_NODES) {
                float v = acc[i][j] + b;
                out[r * HID + o] = v > 0.f ? v : 0.f;
            }
        }
    }
}

// ---------------- gate dots: gd[n] = x[n].w_dst, gs[n] = x[n].w_src ----------------

__global__ void gate_k(const float* __restrict__ x, const float* __restrict__ gw,
                       float* __restrict__ gd, float* __restrict__ gs) {
    int t = blockIdx.x * blockDim.x + threadIdx.x;
    int nid = t >> 6, lane = t & 63;
    if (nid >= N_NODES) return;
    const float* xr = x + nid * HID;
    float a0 = xr[lane], a1 = xr[64 + lane];
    float pd = a0 * gw[lane]       + a1 * gw[64 + lane];
    float ps = a0 * gw[128 + lane] + a1 * gw[192 + lane];
#pragma unroll
    for (int off = 32; off; off >>= 1) {
        pd += __shfl_down(pd, off);
        ps += __shfl_down(ps, off);
    }
    if (lane == 0) { gd[nid] = pd; gs[nid] = ps; }
}

// ---------------- aggregation: one wave per dst node ----------------

__global__ void agg_k(const float* __restrict__ x, const float* __restrict__ raw,
                      const float* __restrict__ gd, const float* __restrict__ gs,
                      const float* __restrict__ d, const int* __restrict__ rowptr,
                      const int* __restrict__ csr, const float* __restrict__ gb, int layer,
                      const float* __restrict__ yw, const float* __restrict__ nw,
                      float* __restrict__ xout) {
    int t = blockIdx.x * blockDim.x + threadIdx.x;
    int nid = t >> 6, lane = t & 63;
    if (nid >= N_NODES) return;
    int c = lane * 2;
    float2 acc = *(const float2*)&raw[nid * HID + c];
    acc.x *= EPS; acc.y *= EPS;
    float gdn = gd[nid] + gb[layer];
    float dn  = d[nid];
    float ty  = fast_tanh(yw[0]);
    float tno = fast_tanh(nw[0]);
    int e0 = rowptr[nid], e1 = rowptr[nid + 1];
    for (int e = e0; e < e1; ++e) {
        int p = csr[e];
        int s = p & 0x7fffffff;
        float ynt  = (p < 0) ? ty : tno;
        float g    = fast_tanh(gdn + gs[s]);
        float coef = (g + ynt) * 0.5f * dn * d[s];
        float2 xs  = *(const float2*)&x[s * HID + c];
        acc.x += coef * xs.x;
        acc.y += coef * xs.y;
    }
    *(float2*)&xout[nid * HID + c] = acc;
}

// ---------------- t2 + log_softmax: 64-node tile per block ----------------

__launch_bounds__(256)
__global__ void out_k(const float* __restrict__ x, const float* __restrict__ w,
                      const float* __restrict__ bias, float* __restrict__ out) {
    __shared__ float As[64][132];   // 64 nodes x 128 k
    __shared__ float Bs[64][132];   // 64 outs  x 128 k
    int tid = threadIdx.x;
    int n0  = blockIdx.x * 64;
#pragma unroll
    for (int j = 0; j < 8; j++) {
        int f4 = tid + j * 256;
        int r = f4 >> 5, c = (f4 & 31) * 4;
        float4 v = make_float4(0.f, 0.f, 0.f, 0.f);
        int gr = n0 + r;
        if (gr < N_NODES) v = *(const float4*)&x[gr * HID + c];
        *(float4*)&As[r][c] = v;
        *(float4*)&Bs[r][c] = *(const float4*)&w[r * HID + c];
    }
    __syncthreads();
    int tn = tid >> 4, to = tid & 15;
    float acc[4][4];
#pragma unroll
    for (int i = 0; i < 4; i++)
#pragma unroll
        for (int j = 0; j < 4; j++) acc[i][j] = 0.0f;
#pragma unroll
    for (int k = 0; k < HID; k += 4) {
        float4 av[4], bv[4];
#pragma unroll
        for (int i = 0; i < 4; i++) av[i] = *(const float4*)&As[tn + 16 * i][k];
#pragma unroll
        for (int j = 0; j < 4; j++) bv[j] = *(const float4*)&Bs[to + 16 * j][k];
#pragma unroll
        for (int i = 0; i < 4; i++)
#pragma unroll
            for (int j = 0; j < 4; j++) {
                acc[i][j] += av[i].x * bv[j].x;
                acc[i][j] += av[i].y * bv[j].y;
                acc[i][j] += av[i].z * bv[j].z;
                acc[i][j] += av[i].w * bv[j].w;
            }
    }
    float bj[4];
#pragma unroll
    for (int j = 0; j < 4; j++) bj[j] = bias[to + 16 * j];
#pragma unroll
    for (int i = 0; i < 4; i++) {
        float v[4];
        float m = -1e30f;
#pragma unroll
        for (int j = 0; j < 4; j++) { v[j] = acc[i][j] + bj[j]; m = fmaxf(m, v[j]); }
#pragma unroll
        for (int s = 1; s < 16; s <<= 1) m = fmaxf(m, __shfl_xor(m, s));
        float sum = 0.f;
#pragma unroll
        for (int j = 0; j < 4; j++) sum += __expf(v[j] - m);
#pragma unroll
        for (int s = 1; s < 16; s <<= 1) sum += __shfl_xor(sum, s);
        float lse = m + __logf(sum);
        int r = n0 + tn + 16 * i;
        if (r < N_NODES) {
#pragma unroll
            for (int j = 0; j < 4; j++) out[r * OUT_DIM + to + 16 * j] = v[j] - lse;
        }
    }
}

// ---------------- launcher ----------------

extern "C" void kernel_launch(void* const* d_in, const int* in_sizes, int n_in,
                              void* d_out, int out_size, void* d_ws, size_t ws_size,
                              hipStream_t stream) {
    const float* h    = (const float*)d_in[0];
    const float* d    = (const float*)d_in[1];
    const float* t1_w = (const float*)d_in[2];
    const float* t1_b = (const float*)d_in[3];
    const float* gw   = (const float*)d_in[4];   // [2][256]
    const float* gb   = (const float*)d_in[5];   // [2]
    const float* t2_w = (const float*)d_in[6];   // [64][128]
    const float* t2_b = (const float*)d_in[7];
    const float* yw   = (const float*)d_in[8];
    const float* nw   = (const float*)d_in[9];
    const int* src    = (const int*)d_in[10];
    const int* dst    = (const int*)d_in[11];
    const int* yn     = (const int*)d_in[12];
    float* outp = (float*)d_out;

    char* ws = (char*)d_ws;
    size_t off = 0;
    auto alloc = [&](size_t bytes) {
        void* p = ws + off;
        off = (off + bytes + 255) & ~(size_t)255;
        return p;
    };
    float* raw    = (float*)alloc((size_t)N_NODES * HID * 4);
    float* xA     = (float*)alloc((size_t)N_NODES * HID * 4);
    float* gdv    = (float*)alloc((size_t)N_NODES * 4);
    float* gsv    = (float*)alloc((size_t)N_NODES * 4);
    int*   deg    = (int*)alloc((size_t)N_NODES * 4);
    int*   rowptr = (int*)alloc((size_t)(N_NODES + 1) * 4);
    int*   cursor = (int*)alloc((size_t)N_NODES * 4);
    int*   csr    = (int*)alloc((size_t)N_EDGES * 4);
    (void)ws_size; (void)n_in; (void)in_sizes; (void)out_size;

    // CSR build
    hipMemsetAsync(deg, 0, (size_t)N_NODES * 4, stream);
    hist_k<<<(N_EDGES + 255) / 256, 256, 0, stream>>>(dst, deg);
    scan_k<<<1, 1024, 0, stream>>>(deg, rowptr, cursor);
    fill_k<<<(N_EDGES + 255) / 256, 256, 0, stream>>>(src, dst, yn, cursor, csr);

    // t1: raw = relu(h @ t1_w^T + b)
    t1_k<<<(N_NODES + 63) / 64, 256, 0, stream>>>(h, t1_w, t1_b, raw);

    int wave_blocks = (N_NODES * 64 + 255) / 256;   // one wave per node

    // layer 0: raw -> xA
    gate_k<<<wave_blocks, 256, 0, stream>>>(raw, gw, gdv, gsv);
    agg_k<<<wave_blocks, 256, 0, stream>>>(raw, raw, gdv, gsv, d, rowptr, csr,
                                           gb, 0, yw, nw, xA);
    // layer 1: xA -> raw (safe: each wave reads raw[n] before writing it)
    gate_k<<<wave_blocks, 256, 0, stream>>>(xA, gw + 256, gdv, gsv);
    agg_k<<<wave_blocks, 256, 0, stream>>>(xA, raw, gdv, gsv, d, rowptr, csr,
                                           gb, 1, yw, nw, raw);

    // t2 + log_softmax
    out_k<<<(N_NODES + 63) / 64, 256, 0, stream>>>(raw, t2_w, t2_b, outp);
}

// Round 2
// 683.904 us; speedup vs baseline: 1.4531x; 1.4531x over previous
//
#include <hip/hip_runtime.h>
#include <math.h>

#define N_NODES 50000
#define N_EDGES 800000
#define IN_DIM  512
#define HID     128
#define OUT_DIM 64
#define EPS     0.3f

__device__ __forceinline__ float fast_tanh(float x) {
    // tanh(x) = 1 - 2/(exp(2x)+1); saturates correctly at +/-inf
    return 1.0f - 2.0f / (__expf(2.0f * x) + 1.0f);
}

// ---------------- CSR build ----------------

__global__ void hist_k(const int* __restrict__ dst, int* __restrict__ deg) {
    int e = blockIdx.x * blockDim.x + threadIdx.x;
    if (e < N_EDGES) atomicAdd(&deg[dst[e]], 1);
}

__global__ void scan_k(const int* __restrict__ deg, int* __restrict__ rowptr,
                       int* __restrict__ cursor) {
    __shared__ int buf[1024];
    __shared__ int carry;
    if (threadIdx.x == 0) carry = 0;
    __syncthreads();
    for (int base = 0; base < N_NODES; base += 1024) {
        int i = base + (int)threadIdx.x;
        int v = (i < N_NODES) ? deg[i] : 0;
        buf[threadIdx.x] = v;
        __syncthreads();
        for (int off = 1; off < 1024; off <<= 1) {
            int t = 0;
            if ((int)threadIdx.x >= off) t = buf[threadIdx.x - off];
            __syncthreads();
            if ((int)threadIdx.x >= off) buf[threadIdx.x] += t;
            __syncthreads();
        }
        int excl = buf[threadIdx.x] - v + carry;  // exclusive prefix + running carry
        if (i < N_NODES) { rowptr[i] = excl; cursor[i] = excl; }
        int tot = buf[1023];
        __syncthreads();
        if (threadIdx.x == 0) carry += tot;
        __syncthreads();
    }
    if (threadIdx.x == 0) rowptr[N_NODES] = carry;
}

__global__ void fill_k(const int* __restrict__ src, const int* __restrict__ dst,
                       const int* __restrict__ yn, int* __restrict__ cursor,
                       int* __restrict__ csr) {
    int e = blockIdx.x * blockDim.x + threadIdx.x;
    if (e >= N_EDGES) return;
    int pos = atomicAdd(&cursor[dst[e]], 1);
    csr[pos] = src[e] | (yn[e] << 31);   // src < 2^17, yn packed in sign bit
}

// ---------------- t1: x = relu(h @ t1_w^T + b), 50000x512 -> 50000x128 ----------------

__launch_bounds__(256)
__global__ void t1_k(const float* __restrict__ h, const float* __restrict__ w,
                     const float* __restrict__ bias, float* __restrict__ out) {
    __shared__ float As[64][36];    // 64 nodes x 32 k (+4 pad, float4-aligned)
    __shared__ float Bs[128][36];   // 128 outs x 32 k
    int tid = threadIdx.x;
    int n0  = blockIdx.x * 64;
    int tn = tid >> 4, to = tid & 15;
    float acc[4][8];
#pragma unroll
    for (int i = 0; i < 4; i++)
#pragma unroll
        for (int j = 0; j < 8; j++) acc[i][j] = 0.0f;

    for (int k0 = 0; k0 < IN_DIM; k0 += 32) {
        // A tile: 64x32 floats = 512 float4, 2 per thread
#pragma unroll
        for (int j = 0; j < 2; j++) {
            int f4 = tid + j * 256;
            int r = f4 >> 3, c = (f4 & 7) * 4;
            int gr = n0 + r;
            float4 v = make_float4(0.f, 0.f, 0.f, 0.f);
            if (gr < N_NODES) v = *(const float4*)&h[gr * IN_DIM + k0 + c];
            *(float4*)&As[r][c] = v;
        }
        // B tile: 128x32 floats = 1024 float4, 4 per thread
#pragma unroll
        for (int j = 0; j < 4; j++) {
            int f4 = tid + j * 256;
            int r = f4 >> 3, c = (f4 & 7) * 4;
            *(float4*)&Bs[r][c] = *(const float4*)&w[r * IN_DIM + k0 + c];
        }
        __syncthreads();
        // unroll capped at 2: full unroll hoists 96 float4 LDS loads -> VGPR
        // spill to scratch (observed VGPR=256 + ~700MB spill traffic in out_k)
#pragma unroll 2
        for (int k = 0; k < 32; k += 4) {
            float4 av[4], bv[8];
#pragma unroll
            for (int i = 0; i < 4; i++) av[i] = *(const float4*)&As[tn + 16 * i][k];
#pragma unroll
            for (int j = 0; j < 8; j++) bv[j] = *(const float4*)&Bs[to + 16 * j][k];
#pragma unroll
            for (int i = 0; i < 4; i++)
#pragma unroll
                for (int j = 0; j < 8; j++) {
                    acc[i][j] += av[i].x * bv[j].x;
                    acc[i][j] += av[i].y * bv[j].y;
                    acc[i][j] += av[i].z * bv[j].z;
                    acc[i][j] += av[i].w * bv[j].w;
                }
        }
        __syncthreads();
    }
#pragma unroll
    for (int j = 0; j < 8; j++) {
        int o = to + 16 * j;
        float b = bias[o];
#pragma unroll
        for (int i = 0; i < 4; i++) {
            int r = n0 + tn + 16 * i;
            if (r < N_NODES) {
                float v = acc[i][j] + b;
                out[r * HID + o] = v > 0.f ? v : 0.f;
            }
        }
    }
}

// ---------------- gate dots: gd[n] = x[n].w_dst, gs[n] = x[n].w_src ----------------

__global__ void gate_k(const float* __restrict__ x, const float* __restrict__ gw,
                       float* __restrict__ gd, float* __restrict__ gs) {
    int t = blockIdx.x * blockDim.x + threadIdx.x;
    int nid = t >> 6, lane = t & 63;
    if (nid >= N_NODES) return;
    const float* xr = x + nid * HID;
    float a0 = xr[lane], a1 = xr[64 + lane];
    float pd = a0 * gw[lane]       + a1 * gw[64 + lane];
    float ps = a0 * gw[128 + lane] + a1 * gw[192 + lane];
#pragma unroll
    for (int off = 32; off; off >>= 1) {
        pd += __shfl_down(pd, off);
        ps += __shfl_down(ps, off);
    }
    if (lane == 0) { gd[nid] = pd; gs[nid] = ps; }
}

// ---------------- aggregation: one wave per dst node ----------------

__global__ void agg_k(const float* __restrict__ x, const float* __restrict__ raw,
                      const float* __restrict__ gd, const float* __restrict__ gs,
                      const float* __restrict__ d, const int* __restrict__ rowptr,
                      const int* __restrict__ csr, const float* __restrict__ gb, int layer,
                      const float* __restrict__ yw, const float* __restrict__ nw,
                      float* __restrict__ xout) {
    int t = blockIdx.x * blockDim.x + threadIdx.x;
    int nid = t >> 6, lane = t & 63;
    if (nid >= N_NODES) return;
    int c = lane * 2;
    float2 acc = *(const float2*)&raw[nid * HID + c];
    acc.x *= EPS; acc.y *= EPS;
    float gdn = gd[nid] + gb[layer];
    float dn  = d[nid];
    float ty  = fast_tanh(yw[0]);
    float tno = fast_tanh(nw[0]);
    int e0 = rowptr[nid], e1 = rowptr[nid + 1];
    for (int e = e0; e < e1; ++e) {
        int p = csr[e];
        int s = p & 0x7fffffff;
        float ynt  = (p < 0) ? ty : tno;
        float g    = fast_tanh(gdn + gs[s]);
        float coef = (g + ynt) * 0.5f * dn * d[s];
        float2 xs  = *(const float2*)&x[s * HID + c];
        acc.x += coef * xs.x;
        acc.y += coef * xs.y;
    }
    *(float2*)&xout[nid * HID + c] = acc;
}

// ---------------- t2 + log_softmax: 64-node tile per block ----------------

__launch_bounds__(256)
__global__ void out_k(const float* __restrict__ x, const float* __restrict__ w,
                      const float* __restrict__ bias, float* __restrict__ out) {
    __shared__ float As[64][132];   // 64 nodes x 128 k
    __shared__ float Bs[64][132];   // 64 outs  x 128 k
    int tid = threadIdx.x;
    int n0  = blockIdx.x * 64;
#pragma unroll
    for (int j = 0; j < 8; j++) {
        int f4 = tid + j * 256;
        int r = f4 >> 5, c = (f4 & 31) * 4;
        float4 v = make_float4(0.f, 0.f, 0.f, 0.f);
        int gr = n0 + r;
        if (gr < N_NODES) v = *(const float4*)&x[gr * HID + c];
        *(float4*)&As[r][c] = v;
        *(float4*)&Bs[r][c] = *(const float4*)&w[r * HID + c];
    }
    __syncthreads();
    int tn = tid >> 4, to = tid & 15;
    float acc[4][4];
#pragma unroll
    for (int i = 0; i < 4; i++)
#pragma unroll
        for (int j = 0; j < 4; j++) acc[i][j] = 0.0f;
    // unroll capped at 2: full unroll of 32 iterations x 8 float4 LDS loads
    // was the VGPR=256 spill (FETCH 379MB / WRITE 348MB, 320us -> spill-bound)
#pragma unroll 2
    for (int k = 0; k < HID; k += 4) {
        float4 av[4], bv[4];
#pragma unroll
        for (int i = 0; i < 4; i++) av[i] = *(const float4*)&As[tn + 16 * i][k];
#pragma unroll
        for (int j = 0; j < 4; j++) bv[j] = *(const float4*)&Bs[to + 16 * j][k];
#pragma unroll
        for (int i = 0; i < 4; i++)
#pragma unroll
            for (int j = 0; j < 4; j++) {
                acc[i][j] += av[i].x * bv[j].x;
                acc[i][j] += av[i].y * bv[j].y;
                acc[i][j] += av[i].z * bv[j].z;
                acc[i][j] += av[i].w * bv[j].w;
            }
    }
    float bj[4];
#pragma unroll
    for (int j = 0; j < 4; j++) bj[j] = bias[to + 16 * j];
#pragma unroll
    for (int i = 0; i < 4; i++) {
        float v[4];
        float m = -1e30f;
#pragma unroll
        for (int j = 0; j < 4; j++) { v[j] = acc[i][j] + bj[j]; m = fmaxf(m, v[j]); }
#pragma unroll
        for (int s = 1; s < 16; s <<= 1) m = fmaxf(m, __shfl_xor(m, s));
        float sum = 0.f;
#pragma unroll
        for (int j = 0; j < 4; j++) sum += __expf(v[j] - m);
#pragma unroll
        for (int s = 1; s < 16; s <<= 1) sum += __shfl_xor(sum, s);
        float lse = m + __logf(sum);
        int r = n0 + tn + 16 * i;
        if (r < N_NODES) {
#pragma unroll
            for (int j = 0; j < 4; j++) out[r * OUT_DIM + to + 16 * j] = v[j] - lse;
        }
    }
}

// ---------------- launcher ----------------

extern "C" void kernel_launch(void* const* d_in, const int* in_sizes, int n_in,
                              void* d_out, int out_size, void* d_ws, size_t ws_size,
                              hipStream_t stream) {
    const float* h    = (const float*)d_in[0];
    const float* d    = (const float*)d_in[1];
    const float* t1_w = (const float*)d_in[2];
    const float* t1_b = (const float*)d_in[3];
    const float* gw   = (const float*)d_in[4];   // [2][256]
    const float* gb   = (const float*)d_in[5];   // [2]
    const float* t2_w = (const float*)d_in[6];   // [64][128]
    const float* t2_b = (const float*)d_in[7];
    const float* yw   = (const float*)d_in[8];
    const float* nw   = (const float*)d_in[9];
    const int* src    = (const int*)d_in[10];
    const int* dst    = (const int*)d_in[11];
    const int* yn     = (const int*)d_in[12];
    float* outp = (float*)d_out;

    char* ws = (char*)d_ws;
    size_t off = 0;
    auto alloc = [&](size_t bytes) {
        void* p = ws + off;
        off = (off + bytes + 255) & ~(size_t)255;
        return p;
    };
    float* raw    = (float*)alloc((size_t)N_NODES * HID * 4);
    float* xA     = (float*)alloc((size_t)N_NODES * HID * 4);
    float* gdv    = (float*)alloc((size_t)N_NODES * 4);
    float* gsv    = (float*)alloc((size_t)N_NODES * 4);
    int*   deg    = (int*)alloc((size_t)N_NODES * 4);
    int*   rowptr = (int*)alloc((size_t)(N_NODES + 1) * 4);
    int*   cursor = (int*)alloc((size_t)N_NODES * 4);
    int*   csr    = (int*)alloc((size_t)N_EDGES * 4);
    (void)ws_size; (void)n_in; (void)in_sizes; (void)out_size;

    // CSR build
    hipMemsetAsync(deg, 0, (size_t)N_NODES * 4, stream);
    hist_k<<<(N_EDGES + 255) / 256, 256, 0, stream>>>(dst, deg);
    scan_k<<<1, 1024, 0, stream>>>(deg, rowptr, cursor);
    fill_k<<<(N_EDGES + 255) / 256, 256, 0, stream>>>(src, dst, yn, cursor, csr);

    // t1: raw = relu(h @ t1_w^T + b)
    t1_k<<<(N_NODES + 63) / 64, 256, 0, stream>>>(h, t1_w, t1_b, raw);

    int wave_blocks = (N_NODES * 64 + 255) / 256;   // one wave per node

    // layer 0: raw -> xA
    gate_k<<<wave_blocks, 256, 0, stream>>>(raw, gw, gdv, gsv);
    agg_k<<<wave_blocks, 256, 0, stream>>>(raw, raw, gdv, gsv, d, rowptr, csr,
                                           gb, 0, yw, nw, xA);
    // layer 1: xA -> raw (safe: each wave reads raw[n] before writing it)
    gate_k<<<wave_blocks, 256, 0, stream>>>(xA, gw + 256, gdv, gsv);
    agg_k<<<wave_blocks, 256, 0, stream>>>(xA, raw, gdv, gsv, d, rowptr, csr,
                                           gb, 1, yw, nw, raw);

    // t2 + log_softmax
    out_k<<<(N_NODES + 63) / 64, 256, 0, stream>>>(raw, t2_w, t2_b, outp);
}

// Round 3
// 630.597 us; speedup vs baseline: 1.5759x; 1.0845x over previous
//
#include <hip/hip_runtime.h>
#include <math.h>

#define N_NODES 50000
#define N_EDGES 800000
#define IN_DIM  512
#define HID     128
#define OUT_DIM 64
#define EPS     0.3f

typedef __attribute__((ext_vector_type(8))) short bf16x8;
typedef __attribute__((ext_vector_type(4))) float f32x4;

__device__ __forceinline__ float fast_tanh(float x) {
    // tanh(x) = 1 - 2/(exp(2x)+1); saturates correctly at +/-inf
    return 1.0f - 2.0f / (__expf(2.0f * x) + 1.0f);
}

__device__ __forceinline__ short cvt_bf16(float f) {
    // round-to-nearest-even truncation fp32 -> bf16
    unsigned u = __float_as_uint(f);
    unsigned r = (u + 0x7fffu + ((u >> 16) & 1u)) >> 16;
    return (short)r;
}

// ---------------- CSR build ----------------

__global__ void hist_k(const int* __restrict__ dst, int* __restrict__ deg) {
    int e = blockIdx.x * blockDim.x + threadIdx.x;
    if (e < N_EDGES) atomicAdd(&deg[dst[e]], 1);
}

__global__ void scan_k(const int* __restrict__ deg, int* __restrict__ rowptr,
                       int* __restrict__ cursor) {
    __shared__ int buf[1024];
    __shared__ int carry;
    if (threadIdx.x == 0) carry = 0;
    __syncthreads();
    for (int base = 0; base < N_NODES; base += 1024) {
        int i = base + (int)threadIdx.x;
        int v = (i < N_NODES) ? deg[i] : 0;
        buf[threadIdx.x] = v;
        __syncthreads();
        for (int off = 1; off < 1024; off <<= 1) {
            int t = 0;
            if ((int)threadIdx.x >= off) t = buf[threadIdx.x - off];
            __syncthreads();
            if ((int)threadIdx.x >= off) buf[threadIdx.x] += t;
            __syncthreads();
        }
        int excl = buf[threadIdx.x] - v + carry;  // exclusive prefix + running carry
        if (i < N_NODES) { rowptr[i] = excl; cursor[i] = excl; }
        int tot = buf[1023];
        __syncthreads();
        if (threadIdx.x == 0) carry += tot;
        __syncthreads();
    }
    if (threadIdx.x == 0) rowptr[N_NODES] = carry;
}

__global__ void fill_k(const int* __restrict__ src, const int* __restrict__ dst,
                       const int* __restrict__ yn, int* __restrict__ cursor,
                       int* __restrict__ csr) {
    int e = blockIdx.x * blockDim.x + threadIdx.x;
    if (e >= N_EDGES) return;
    int pos = atomicAdd(&cursor[dst[e]], 1);
    csr[pos] = src[e] | (yn[e] << 31);   // src < 2^17, yn packed in sign bit
}

// ---------------- t1 (bf16 MFMA): x = relu(h @ t1_w^T + b), 50000x512 -> 50000x128 ----
// C = H * W^T, both row-major -> A and B fragments load identically from
// row-major LDS tiles: 8 contiguous bf16 at [row = tile+lane&15][k + (lane>>4)*8].
// C/D layout: col = lane&15, row = (lane>>4)*4 + reg.

__launch_bounds__(256)
__global__ void t1_k(const float* __restrict__ h, const float* __restrict__ w,
                     const float* __restrict__ bias, float* __restrict__ out) {
    // +8 bf16 pad (16B) keeps 16B alignment; row stride 68 dwords == 4 mod 32
    // -> worst aliasing 2-way across a 16-lane fragment read, which is free.
    __shared__ short As[64][136];    // 64 nodes  x 128 k (bf16)
    __shared__ short Bs[128][136];   // 128 outs  x 128 k (bf16)
    int tid  = threadIdx.x;
    int n0   = blockIdx.x * 64;
    int lane = tid & 63;
    int wv   = tid >> 6;          // wave 0..3 -> output cols wv*32 .. wv*32+31
    int l15  = lane & 15;
    int quad = lane >> 4;

    f32x4 acc[4][2];
#pragma unroll
    for (int i = 0; i < 4; i++)
#pragma unroll
        for (int j = 0; j < 2; j++) acc[i][j] = (f32x4){0.f, 0.f, 0.f, 0.f};

    for (int k0 = 0; k0 < IN_DIM; k0 += 128) {
        // stage A: 64 rows x 128 k = 1024 groups of 8 floats -> bf16
#pragma unroll
        for (int i = 0; i < 4; ++i) {
            int f8 = i * 256 + tid;
            int r  = f8 >> 4;
            int kc = (f8 & 15) * 8;
            int gr = n0 + r;
            float4 v0 = make_float4(0.f, 0.f, 0.f, 0.f), v1 = v0;
            if (gr < N_NODES) {
                v0 = *(const float4*)&h[(size_t)gr * IN_DIM + k0 + kc];
                v1 = *(const float4*)&h[(size_t)gr * IN_DIM + k0 + kc + 4];
            }
            bf16x8 s;
            s[0] = cvt_bf16(v0.x); s[1] = cvt_bf16(v0.y);
            s[2] = cvt_bf16(v0.z); s[3] = cvt_bf16(v0.w);
            s[4] = cvt_bf16(v1.x); s[5] = cvt_bf16(v1.y);
            s[6] = cvt_bf16(v1.z); s[7] = cvt_bf16(v1.w);
            *(bf16x8*)&As[r][kc] = s;
        }
        // stage B: 128 rows x 128 k = 2048 groups of 8 floats -> bf16
#pragma unroll
        for (int i = 0; i < 8; ++i) {
            int f8 = i * 256 + tid;
            int r  = f8 >> 4;
            int kc = (f8 & 15) * 8;
            float4 v0 = *(const float4*)&w[(size_t)r * IN_DIM + k0 + kc];
            float4 v1 = *(const float4*)&w[(size_t)r * IN_DIM + k0 + kc + 4];
            bf16x8 s;
            s[0] = cvt_bf16(v0.x); s[1] = cvt_bf16(v0.y);
            s[2] = cvt_bf16(v0.z); s[3] = cvt_bf16(v0.w);
            s[4] = cvt_bf16(v1.x); s[5] = cvt_bf16(v1.y);
            s[6] = cvt_bf16(v1.z); s[7] = cvt_bf16(v1.w);
            *(bf16x8*)&Bs[r][kc] = s;
        }
        __syncthreads();
#pragma unroll 2
        for (int ks = 0; ks < 128; ks += 32) {
            bf16x8 af[4], bf[2];
#pragma unroll
            for (int rt = 0; rt < 4; ++rt)
                af[rt] = *(const bf16x8*)&As[rt * 16 + l15][ks + quad * 8];
#pragma unroll
            for (int ct = 0; ct < 2; ++ct)
                bf[ct] = *(const bf16x8*)&Bs[wv * 32 + ct * 16 + l15][ks + quad * 8];
#pragma unroll
            for (int rt = 0; rt < 4; ++rt)
#pragma unroll
                for (int ct = 0; ct < 2; ++ct)
                    acc[rt][ct] = __builtin_amdgcn_mfma_f32_16x16x32_bf16(
                        af[rt], bf[ct], acc[rt][ct], 0, 0, 0);
        }
        __syncthreads();
    }
    // epilogue: bias + relu
#pragma unroll
    for (int ct = 0; ct < 2; ++ct) {
        int o = wv * 32 + ct * 16 + l15;
        float b = bias[o];
#pragma unroll
        for (int rt = 0; rt < 4; ++rt) {
#pragma unroll
            for (int r = 0; r < 4; ++r) {
                int node = n0 + rt * 16 + quad * 4 + r;
                if (node < N_NODES) {
                    float v = acc[rt][ct][r] + b;
                    out[(size_t)node * HID + o] = v > 0.f ? v : 0.f;
                }
            }
        }
    }
}

// ---------------- gate dots: gd[n] = x[n].w_dst, gs[n] = x[n].w_src ----------------

__global__ void gate_k(const float* __restrict__ x, const float* __restrict__ gw,
                       float* __restrict__ gd, float* __restrict__ gs) {
    int t = blockIdx.x * blockDim.x + threadIdx.x;
    int nid = t >> 6, lane = t & 63;
    if (nid >= N_NODES) return;
    const float* xr = x + nid * HID;
    float a0 = xr[lane], a1 = xr[64 + lane];
    float pd = a0 * gw[lane]       + a1 * gw[64 + lane];
    float ps = a0 * gw[128 + lane] + a1 * gw[192 + lane];
#pragma unroll
    for (int off = 32; off; off >>= 1) {
        pd += __shfl_down(pd, off);
        ps += __shfl_down(ps, off);
    }
    if (lane == 0) { gd[nid] = pd; gs[nid] = ps; }
}

// ---------------- aggregation: one wave per dst node ----------------

__global__ void agg_k(const float* __restrict__ x, const float* __restrict__ raw,
                      const float* __restrict__ gd, const float* __restrict__ gs,
                      const float* __restrict__ d, const int* __restrict__ rowptr,
                      const int* __restrict__ csr, const float* __restrict__ gb, int layer,
                      const float* __restrict__ yw, const float* __restrict__ nw,
                      float* __restrict__ xout) {
    int t = blockIdx.x * blockDim.x + threadIdx.x;
    int nid = t >> 6, lane = t & 63;
    if (nid >= N_NODES) return;
    int c = lane * 2;
    float2 acc = *(const float2*)&raw[nid * HID + c];
    acc.x *= EPS; acc.y *= EPS;
    float gdn = gd[nid] + gb[layer];
    float dn  = d[nid];
    float ty  = fast_tanh(yw[0]);
    float tno = fast_tanh(nw[0]);
    int e0 = rowptr[nid], e1 = rowptr[nid + 1];
    for (int e = e0; e < e1; ++e) {
        int p = csr[e];
        int s = p & 0x7fffffff;
        float ynt  = (p < 0) ? ty : tno;
        float g    = fast_tanh(gdn + gs[s]);
        float coef = (g + ynt) * 0.5f * dn * d[s];
        float2 xs  = *(const float2*)&x[s * HID + c];
        acc.x += coef * xs.x;
        acc.y += coef * xs.y;
    }
    *(float2*)&xout[nid * HID + c] = acc;
}

// ---------------- t2 + log_softmax: 64-node tile per block ----------------

__launch_bounds__(256)
__global__ void out_k(const float* __restrict__ x, const float* __restrict__ w,
                      const float* __restrict__ bias, float* __restrict__ out) {
    __shared__ float As[64][132];   // 64 nodes x 128 k
    __shared__ float Bs[64][132];   // 64 outs  x 128 k
    int tid = threadIdx.x;
    int n0  = blockIdx.x * 64;
#pragma unroll
    for (int j = 0; j < 8; j++) {
        int f4 = tid + j * 256;
        int r = f4 >> 5, c = (f4 & 31) * 4;
        float4 v = make_float4(0.f, 0.f, 0.f, 0.f);
        int gr = n0 + r;
        if (gr < N_NODES) v = *(const float4*)&x[gr * HID + c];
        *(float4*)&As[r][c] = v;
        *(float4*)&Bs[r][c] = *(const float4*)&w[r * HID + c];
    }
    __syncthreads();
    int tn = tid >> 4, to = tid & 15;
    float acc[4][4];
#pragma unroll
    for (int i = 0; i < 4; i++)
#pragma unroll
        for (int j = 0; j < 4; j++) acc[i][j] = 0.0f;
    // unroll capped at 2: full unroll of 32 iterations x 8 float4 LDS loads
    // was the VGPR=256 spill (FETCH 379MB / WRITE 348MB, 320us -> spill-bound)
#pragma unroll 2
    for (int k = 0; k < HID; k += 4) {
        float4 av[4], bv[4];
#pragma unroll
        for (int i = 0; i < 4; i++) av[i] = *(const float4*)&As[tn + 16 * i][k];
#pragma unroll
        for (int j = 0; j < 4; j++) bv[j] = *(const float4*)&Bs[to + 16 * j][k];
#pragma unroll
        for (int i = 0; i < 4; i++)
#pragma unroll
            for (int j = 0; j < 4; j++) {
                acc[i][j] += av[i].x * bv[j].x;
                acc[i][j] += av[i].y * bv[j].y;
                acc[i][j] += av[i].z * bv[j].z;
                acc[i][j] += av[i].w * bv[j].w;
            }
    }
    float bj[4];
#pragma unroll
    for (int j = 0; j < 4; j++) bj[j] = bias[to + 16 * j];
#pragma unroll
    for (int i = 0; i < 4; i++) {
        float v[4];
        float m = -1e30f;
#pragma unroll
        for (int j = 0; j < 4; j++) { v[j] = acc[i][j] + bj[j]; m = fmaxf(m, v[j]); }
#pragma unroll
        for (int s = 1; s < 16; s <<= 1) m = fmaxf(m, __shfl_xor(m, s));
        float sum = 0.f;
#pragma unroll
        for (int j = 0; j < 4; j++) sum += __expf(v[j] - m);
#pragma unroll
        for (int s = 1; s < 16; s <<= 1) sum += __shfl_xor(sum, s);
        float lse = m + __logf(sum);
        int r = n0 + tn + 16 * i;
        if (r < N_NODES) {
#pragma unroll
            for (int j = 0; j < 4; j++) out[r * OUT_DIM + to + 16 * j] = v[j] - lse;
        }
    }
}

// ---------------- launcher ----------------

extern "C" void kernel_launch(void* const* d_in, const int* in_sizes, int n_in,
                              void* d_out, int out_size, void* d_ws, size_t ws_size,
                              hipStream_t stream) {
    const float* h    = (const float*)d_in[0];
    const float* d    = (const float*)d_in[1];
    const float* t1_w = (const float*)d_in[2];
    const float* t1_b = (const float*)d_in[3];
    const float* gw   = (const float*)d_in[4];   // [2][256]
    const float* gb   = (const float*)d_in[5];   // [2]
    const float* t2_w = (const float*)d_in[6];   // [64][128]
    const float* t2_b = (const float*)d_in[7];
    const float* yw   = (const float*)d_in[8];
    const float* nw   = (const float*)d_in[9];
    const int* src    = (const int*)d_in[10];
    const int* dst    = (const int*)d_in[11];
    const int* yn     = (const int*)d_in[12];
    float* outp = (float*)d_out;

    char* ws = (char*)d_ws;
    size_t off = 0;
    auto alloc = [&](size_t bytes) {
        void* p = ws + off;
        off = (off + bytes + 255) & ~(size_t)255;
        return p;
    };
    float* raw    = (float*)alloc((size_t)N_NODES * HID * 4);
    float* xA     = (float*)alloc((size_t)N_NODES * HID * 4);
    float* gdv    = (float*)alloc((size_t)N_NODES * 4);
    float* gsv    = (float*)alloc((size_t)N_NODES * 4);
    int*   deg    = (int*)alloc((size_t)N_NODES * 4);
    int*   rowptr = (int*)alloc((size_t)(N_NODES + 1) * 4);
    int*   cursor = (int*)alloc((size_t)N_NODES * 4);
    int*   csr    = (int*)alloc((size_t)N_EDGES * 4);
    (void)ws_size; (void)n_in; (void)in_sizes; (void)out_size;

    // CSR build
    hipMemsetAsync(deg, 0, (size_t)N_NODES * 4, stream);
    hist_k<<<(N_EDGES + 255) / 256, 256, 0, stream>>>(dst, deg);
    scan_k<<<1, 1024, 0, stream>>>(deg, rowptr, cursor);
    fill_k<<<(N_EDGES + 255) / 256, 256, 0, stream>>>(src, dst, yn, cursor, csr);

    // t1: raw = relu(h @ t1_w^T + b)  [bf16 MFMA]
    t1_k<<<(N_NODES + 63) / 64, 256, 0, stream>>>(h, t1_w, t1_b, raw);

    int wave_blocks = (N_NODES * 64 + 255) / 256;   // one wave per node

    // layer 0: raw -> xA
    gate_k<<<wave_blocks, 256, 0, stream>>>(raw, gw, gdv, gsv);
    agg_k<<<wave_blocks, 256, 0, stream>>>(raw, raw, gdv, gsv, d, rowptr, csr,
                                           gb, 0, yw, nw, xA);
    // layer 1: xA -> raw (safe: each wave reads raw[n] before writing it)
    gate_k<<<wave_blocks, 256, 0, stream>>>(xA, gw + 256, gdv, gsv);
    agg_k<<<wave_blocks, 256, 0, stream>>>(xA, raw, gdv, gsv, d, rowptr, csr,
                                           gb, 1, yw, nw, raw);

    // t2 + log_softmax
    out_k<<<(N_NODES + 63) / 64, 256, 0, stream>>>(raw, t2_w, t2_b, outp);
}

// Round 4
// 455.173 us; speedup vs baseline: 2.1833x; 1.3854x over previous
//
#include <hip/hip_runtime.h>
#include <math.h>

#define N_NODES 50000
#define N_EDGES 800000
#define IN_DIM  512
#define HID     128
#define OUT_DIM 64
#define EPS     0.3f

#define SCAN_BLOCKS 49   // ceil(50000 / 1024)

typedef __attribute__((ext_vector_type(8))) short bf16x8;
typedef __attribute__((ext_vector_type(4))) float f32x4;

__device__ __forceinline__ float fast_tanh(float x) {
    // tanh(x) = 1 - 2/(exp(2x)+1); saturates correctly at +/-inf
    return 1.0f - 2.0f / (__expf(2.0f * x) + 1.0f);
}

__device__ __forceinline__ unsigned cvt_bf16_u(float f) {
    // round-to-nearest-even fp32 -> bf16 (bits in low 16)
    unsigned u = __float_as_uint(f);
    return (u + 0x7fffu + ((u >> 16) & 1u)) >> 16;
}
__device__ __forceinline__ short cvt_bf16(float f) { return (short)cvt_bf16_u(f); }
__device__ __forceinline__ float bf_lo(unsigned u) { return __uint_as_float(u << 16); }
__device__ __forceinline__ float bf_hi(unsigned u) { return __uint_as_float(u & 0xffff0000u); }

// ---------------- CSR build ----------------

__global__ void hist_k(const int* __restrict__ dst, int* __restrict__ deg) {
    int e = blockIdx.x * blockDim.x + threadIdx.x;
    if (e < N_EDGES) atomicAdd(&deg[dst[e]], 1);
}

// 49 blocks x 256 threads x 4 elems: per-block degree sums
__global__ void partial_k(const int* __restrict__ deg, int* __restrict__ partials) {
    int base = blockIdx.x * 1024 + threadIdx.x * 4;
    int s = 0;
#pragma unroll
    for (int j = 0; j < 4; j++) if (base + j < N_NODES) s += deg[base + j];
#pragma unroll
    for (int off = 32; off; off >>= 1) s += __shfl_down(s, off);
    __shared__ int ws[4];
    int lane = threadIdx.x & 63, wv = threadIdx.x >> 6;
    if (lane == 0) ws[wv] = s;
    __syncthreads();
    if (threadIdx.x == 0) partials[blockIdx.x] = ws[0] + ws[1] + ws[2] + ws[3];
}

// exclusive scan of 49 partials (single lane; 49 adds) + rowptr[N]
__global__ void scanp_k(const int* __restrict__ partials, int* __restrict__ bofs,
                        int* __restrict__ rowptr) {
    if (threadIdx.x == 0) {
        int a = 0;
        for (int i = 0; i < SCAN_BLOCKS; i++) { bofs[i] = a; a += partials[i]; }
        rowptr[N_NODES] = a;
    }
}

// 49 blocks: block-internal exclusive scan + block offset -> rowptr/cursor
__global__ void scanw_k(const int* __restrict__ deg, const int* __restrict__ bofs,
                        int* __restrict__ rowptr, int* __restrict__ cursor) {
    int base = blockIdx.x * 1024 + threadIdx.x * 4;
    int v[4]; int s = 0;
#pragma unroll
    for (int j = 0; j < 4; j++) {
        v[j] = (base + j < N_NODES) ? deg[base + j] : 0;
        s += v[j];
    }
    int lane = threadIdx.x & 63, wv = threadIdx.x >> 6;
    int sc = s;
#pragma unroll
    for (int off = 1; off < 64; off <<= 1) {
        int t = __shfl_up(sc, off);
        if (lane >= off) sc += t;
    }
    __shared__ int wtot[4];
    if (lane == 63) wtot[wv] = sc;
    __syncthreads();
    int wof = 0;
    for (int w = 0; w < wv; w++) wof += wtot[w];
    int excl = bofs[blockIdx.x] + wof + (sc - s);
#pragma unroll
    for (int j = 0; j < 4; j++) {
        if (base + j < N_NODES) { rowptr[base + j] = excl; cursor[base + j] = excl; }
        excl += v[j];
    }
}

__global__ void fill_k(const int* __restrict__ src, const int* __restrict__ dst,
                       const int* __restrict__ yn, int* __restrict__ cursor,
                       int* __restrict__ csr, int* __restrict__ edst) {
    int e = blockIdx.x * blockDim.x + threadIdx.x;
    if (e >= N_EDGES) return;
    int dv = dst[e];
    int pos = atomicAdd(&cursor[dv], 1);
    csr[pos]  = src[e] | (yn[e] << 31);   // src < 2^17, yn packed in sign bit
    edst[pos] = dv;
}

// ---------------- t1 (bf16 MFMA): x = relu(h @ t1_w^T + b) -> fp32 raw + bf16 xb0 ----

__launch_bounds__(256)
__global__ void t1_k(const float* __restrict__ h, const float* __restrict__ w,
                     const float* __restrict__ bias, float* __restrict__ out,
                     unsigned short* __restrict__ outb) {
    __shared__ short As[64][136];    // 64 nodes  x 128 k (bf16), +8 pad
    __shared__ short Bs[128][136];   // 128 outs  x 128 k (bf16)
    int tid  = threadIdx.x;
    int n0   = blockIdx.x * 64;
    int lane = tid & 63;
    int wv   = tid >> 6;
    int l15  = lane & 15;
    int quad = lane >> 4;

    f32x4 acc[4][2];
#pragma unroll
    for (int i = 0; i < 4; i++)
#pragma unroll
        for (int j = 0; j < 2; j++) acc[i][j] = (f32x4){0.f, 0.f, 0.f, 0.f};

    for (int k0 = 0; k0 < IN_DIM; k0 += 128) {
#pragma unroll
        for (int i = 0; i < 4; ++i) {
            int f8 = i * 256 + tid;
            int r  = f8 >> 4;
            int kc = (f8 & 15) * 8;
            int gr = n0 + r;
            float4 v0 = make_float4(0.f, 0.f, 0.f, 0.f), v1 = v0;
            if (gr < N_NODES) {
                v0 = *(const float4*)&h[(size_t)gr * IN_DIM + k0 + kc];
                v1 = *(const float4*)&h[(size_t)gr * IN_DIM + k0 + kc + 4];
            }
            bf16x8 s;
            s[0] = cvt_bf16(v0.x); s[1] = cvt_bf16(v0.y);
            s[2] = cvt_bf16(v0.z); s[3] = cvt_bf16(v0.w);
            s[4] = cvt_bf16(v1.x); s[5] = cvt_bf16(v1.y);
            s[6] = cvt_bf16(v1.z); s[7] = cvt_bf16(v1.w);
            *(bf16x8*)&As[r][kc] = s;
        }
#pragma unroll
        for (int i = 0; i < 8; ++i) {
            int f8 = i * 256 + tid;
            int r  = f8 >> 4;
            int kc = (f8 & 15) * 8;
            float4 v0 = *(const float4*)&w[(size_t)r * IN_DIM + k0 + kc];
            float4 v1 = *(const float4*)&w[(size_t)r * IN_DIM + k0 + kc + 4];
            bf16x8 s;
            s[0] = cvt_bf16(v0.x); s[1] = cvt_bf16(v0.y);
            s[2] = cvt_bf16(v0.z); s[3] = cvt_bf16(v0.w);
            s[4] = cvt_bf16(v1.x); s[5] = cvt_bf16(v1.y);
            s[6] = cvt_bf16(v1.z); s[7] = cvt_bf16(v1.w);
            *(bf16x8*)&Bs[r][kc] = s;
        }
        __syncthreads();
#pragma unroll 2
        for (int ks = 0; ks < 128; ks += 32) {
            bf16x8 af[4], bf[2];
#pragma unroll
            for (int rt = 0; rt < 4; ++rt)
                af[rt] = *(const bf16x8*)&As[rt * 16 + l15][ks + quad * 8];
#pragma unroll
            for (int ct = 0; ct < 2; ++ct)
                bf[ct] = *(const bf16x8*)&Bs[wv * 32 + ct * 16 + l15][ks + quad * 8];
#pragma unroll
            for (int rt = 0; rt < 4; ++rt)
#pragma unroll
                for (int ct = 0; ct < 2; ++ct)
                    acc[rt][ct] = __builtin_amdgcn_mfma_f32_16x16x32_bf16(
                        af[rt], bf[ct], acc[rt][ct], 0, 0, 0);
        }
        __syncthreads();
    }
#pragma unroll
    for (int ct = 0; ct < 2; ++ct) {
        int o = wv * 32 + ct * 16 + l15;
        float b = bias[o];
#pragma unroll
        for (int rt = 0; rt < 4; ++rt) {
#pragma unroll
            for (int r = 0; r < 4; ++r) {
                int node = n0 + rt * 16 + quad * 4 + r;
                if (node < N_NODES) {
                    float v = acc[rt][ct][r] + b;
                    v = v > 0.f ? v : 0.f;
                    out[(size_t)node * HID + o]  = v;
                    outb[(size_t)node * HID + o] = (unsigned short)cvt_bf16_u(v);
                }
            }
        }
    }
}

// ---------------- gate dots from bf16 x: gd[n], gs[n] ----------------

__global__ void gate_k(const unsigned short* __restrict__ xb, const float* __restrict__ gw,
                       float* __restrict__ gd, float* __restrict__ gs) {
    int t = blockIdx.x * blockDim.x + threadIdx.x;
    int nid = t >> 6, lane = t & 63;
    if (nid >= N_NODES) return;
    unsigned u = *(const unsigned*)&xb[(size_t)nid * HID + lane * 2];
    float a0 = bf_lo(u), a1 = bf_hi(u);
    float2 wd = *(const float2*)&gw[lane * 2];
    float2 ws = *(const float2*)&gw[128 + lane * 2];
    float pd = a0 * wd.x + a1 * wd.y;
    float ps = a0 * ws.x + a1 * ws.y;
#pragma unroll
    for (int off = 32; off; off >>= 1) {
        pd += __shfl_down(pd, off);
        ps += __shfl_down(ps, off);
    }
    if (lane == 0) { gd[nid] = pd; gs[nid] = ps; }
}

// ---------------- per-edge coefficient (CSR order) ----------------

__global__ void coef_k(const int* __restrict__ csr, const int* __restrict__ edst,
                       const float* __restrict__ gd, const float* __restrict__ gs,
                       const float* __restrict__ d, const float* __restrict__ gb, int layer,
                       const float* __restrict__ yw, const float* __restrict__ nw,
                       float* __restrict__ coef) {
    int e = blockIdx.x * blockDim.x + threadIdx.x;
    if (e >= N_EDGES) return;
    int p = csr[e];
    int s = p & 0x7fffffff;
    int dn = edst[e];
    float ty  = fast_tanh(yw[0]);
    float tno = fast_tanh(nw[0]);
    float ynt = (p < 0) ? ty : tno;
    float g = fast_tanh(gd[dn] + gs[s] + gb[layer]);
    coef[e] = (g + ynt) * 0.5f * d[dn] * d[s];
}

// ---------------- aggregation: one wave per dst node, 4 edges/trip ----------------
// lanes grouped 16/edge; each lane holds 8 elems (16B bf16 gather); xor-fold at end.

__global__ void agg_k(const unsigned short* __restrict__ xb, const float* __restrict__ raw,
                      const int* __restrict__ rowptr, const int* __restrict__ csr,
                      const float* __restrict__ coef,
                      float* __restrict__ outf, unsigned short* __restrict__ outb) {
    int t = blockIdx.x * blockDim.x + threadIdx.x;
    int nid = t >> 6, lane = t & 63;
    if (nid >= N_NODES) return;
    int l15 = lane & 15, eg = lane >> 4;
    float acc[8];
    if (lane < 16) {
        const float4* rr = (const float4*)&raw[(size_t)nid * HID + l15 * 8];
        float4 r0 = rr[0], r1 = rr[1];
        acc[0] = EPS * r0.x; acc[1] = EPS * r0.y; acc[2] = EPS * r0.z; acc[3] = EPS * r0.w;
        acc[4] = EPS * r1.x; acc[5] = EPS * r1.y; acc[6] = EPS * r1.z; acc[7] = EPS * r1.w;
    } else {
#pragma unroll
        for (int j = 0; j < 8; j++) acc[j] = 0.f;
    }
    int e0 = rowptr[nid], e1 = rowptr[nid + 1];
    for (int eb = e0; eb < e1; eb += 4) {
        int e = eb + eg;
        if (e < e1) {
            int p = csr[e];
            int s = p & 0x7fffffff;
            float cf = coef[e];
            uint4 v = *(const uint4*)&xb[(size_t)s * HID + l15 * 8];
            acc[0] += cf * bf_lo(v.x); acc[1] += cf * bf_hi(v.x);
            acc[2] += cf * bf_lo(v.y); acc[3] += cf * bf_hi(v.y);
            acc[4] += cf * bf_lo(v.z); acc[5] += cf * bf_hi(v.z);
            acc[6] += cf * bf_lo(v.w); acc[7] += cf * bf_hi(v.w);
        }
    }
#pragma unroll
    for (int j = 0; j < 8; j++) acc[j] += __shfl_xor(acc[j], 32);
#pragma unroll
    for (int j = 0; j < 8; j++) acc[j] += __shfl_xor(acc[j], 16);
    if (lane < 16) {
        if (outf) {
            float4* of = (float4*)&outf[(size_t)nid * HID + l15 * 8];
            of[0] = make_float4(acc[0], acc[1], acc[2], acc[3]);
            of[1] = make_float4(acc[4], acc[5], acc[6], acc[7]);
        }
        if (outb) {
            uint4 pk;
            pk.x = cvt_bf16_u(acc[0]) | (cvt_bf16_u(acc[1]) << 16);
            pk.y = cvt_bf16_u(acc[2]) | (cvt_bf16_u(acc[3]) << 16);
            pk.z = cvt_bf16_u(acc[4]) | (cvt_bf16_u(acc[5]) << 16);
            pk.w = cvt_bf16_u(acc[6]) | (cvt_bf16_u(acc[7]) << 16);
            *(uint4*)&outb[(size_t)nid * HID + l15 * 8] = pk;
        }
    }
}

// ---------------- t2 + log_softmax: 64-node tile per block ----------------

__launch_bounds__(256)
__global__ void out_k(const float* __restrict__ x, const float* __restrict__ w,
                      const float* __restrict__ bias, float* __restrict__ out) {
    __shared__ float As[64][132];   // 64 nodes x 128 k
    __shared__ float Bs[64][132];   // 64 outs  x 128 k
    int tid = threadIdx.x;
    int n0  = blockIdx.x * 64;
#pragma unroll
    for (int j = 0; j < 8; j++) {
        int f4 = tid + j * 256;
        int r = f4 >> 5, c = (f4 & 31) * 4;
        float4 v = make_float4(0.f, 0.f, 0.f, 0.f);
        int gr = n0 + r;
        if (gr < N_NODES) v = *(const float4*)&x[gr * HID + c];
        *(float4*)&As[r][c] = v;
        *(float4*)&Bs[r][c] = *(const float4*)&w[r * HID + c];
    }
    __syncthreads();
    int tn = tid >> 4, to = tid & 15;
    float acc[4][4];
#pragma unroll
    for (int i = 0; i < 4; i++)
#pragma unroll
        for (int j = 0; j < 4; j++) acc[i][j] = 0.0f;
    // unroll capped at 2: full unroll was the VGPR=256 spill (R1)
#pragma unroll 2
    for (int k = 0; k < HID; k += 4) {
        float4 av[4], bv[4];
#pragma unroll
        for (int i = 0; i < 4; i++) av[i] = *(const float4*)&As[tn + 16 * i][k];
#pragma unroll
        for (int j = 0; j < 4; j++) bv[j] = *(const float4*)&Bs[to + 16 * j][k];
#pragma unroll
        for (int i = 0; i < 4; i++)
#pragma unroll
            for (int j = 0; j < 4; j++) {
                acc[i][j] += av[i].x * bv[j].x;
                acc[i][j] += av[i].y * bv[j].y;
                acc[i][j] += av[i].z * bv[j].z;
                acc[i][j] += av[i].w * bv[j].w;
            }
    }
    float bj[4];
#pragma unroll
    for (int j = 0; j < 4; j++) bj[j] = bias[to + 16 * j];
#pragma unroll
    for (int i = 0; i < 4; i++) {
        float v[4];
        float m = -1e30f;
#pragma unroll
        for (int j = 0; j < 4; j++) { v[j] = acc[i][j] + bj[j]; m = fmaxf(m, v[j]); }
#pragma unroll
        for (int s = 1; s < 16; s <<= 1) m = fmaxf(m, __shfl_xor(m, s));
        float sum = 0.f;
#pragma unroll
        for (int j = 0; j < 4; j++) sum += __expf(v[j] - m);
#pragma unroll
        for (int s = 1; s < 16; s <<= 1) sum += __shfl_xor(sum, s);
        float lse = m + __logf(sum);
        int r = n0 + tn + 16 * i;
        if (r < N_NODES) {
#pragma unroll
            for (int j = 0; j < 4; j++) out[r * OUT_DIM + to + 16 * j] = v[j] - lse;
        }
    }
}

// ---------------- launcher ----------------

extern "C" void kernel_launch(void* const* d_in, const int* in_sizes, int n_in,
                              void* d_out, int out_size, void* d_ws, size_t ws_size,
                              hipStream_t stream) {
    const float* h    = (const float*)d_in[0];
    const float* d    = (const float*)d_in[1];
    const float* t1_w = (const float*)d_in[2];
    const float* t1_b = (const float*)d_in[3];
    const float* gw   = (const float*)d_in[4];   // [2][256]
    const float* gb   = (const float*)d_in[5];   // [2]
    const float* t2_w = (const float*)d_in[6];   // [64][128]
    const float* t2_b = (const float*)d_in[7];
    const float* yw   = (const float*)d_in[8];
    const float* nw   = (const float*)d_in[9];
    const int* src    = (const int*)d_in[10];
    const int* dst    = (const int*)d_in[11];
    const int* yn     = (const int*)d_in[12];
    float* outp = (float*)d_out;

    char* ws = (char*)d_ws;
    size_t off = 0;
    auto alloc = [&](size_t bytes) {
        void* p = ws + off;
        off = (off + bytes + 255) & ~(size_t)255;
        return p;
    };
    float*          raw    = (float*)alloc((size_t)N_NODES * HID * 4);
    unsigned short* xb0    = (unsigned short*)alloc((size_t)N_NODES * HID * 2);
    unsigned short* xb1    = (unsigned short*)alloc((size_t)N_NODES * HID * 2);
    float* gdv    = (float*)alloc((size_t)N_NODES * 4);
    float* gsv    = (float*)alloc((size_t)N_NODES * 4);
    int*   deg    = (int*)alloc((size_t)N_NODES * 4);
    int*   rowptr = (int*)alloc((size_t)(N_NODES + 1) * 4);
    int*   cursor = (int*)alloc((size_t)N_NODES * 4);
    int*   csr    = (int*)alloc((size_t)N_EDGES * 4);
    int*   edst   = (int*)alloc((size_t)N_EDGES * 4);
    float* coef   = (float*)alloc((size_t)N_EDGES * 4);
    int*   partials = (int*)alloc(64 * 4);
    int*   bofs     = (int*)alloc(64 * 4);
    (void)ws_size; (void)n_in; (void)in_sizes; (void)out_size;

    // CSR build (parallel scan: 49-block partials -> 1-wave scan -> 49-block write)
    hipMemsetAsync(deg, 0, (size_t)N_NODES * 4, stream);
    hist_k<<<(N_EDGES + 255) / 256, 256, 0, stream>>>(dst, deg);
    partial_k<<<SCAN_BLOCKS, 256, 0, stream>>>(deg, partials);
    scanp_k<<<1, 64, 0, stream>>>(partials, bofs, rowptr);
    scanw_k<<<SCAN_BLOCKS, 256, 0, stream>>>(deg, bofs, rowptr, cursor);
    fill_k<<<(N_EDGES + 255) / 256, 256, 0, stream>>>(src, dst, yn, cursor, csr, edst);

    // t1: raw(fp32) + xb0(bf16) = relu(h @ t1_w^T + b)  [bf16 MFMA]
    t1_k<<<(N_NODES + 63) / 64, 256, 0, stream>>>(h, t1_w, t1_b, raw, xb0);

    int wave_blocks = (N_NODES * 64 + 255) / 256;   // one wave per node
    int edge_blocks = (N_EDGES + 255) / 256;

    // layer 0: gathers from xb0, writes xb1 (bf16 only)
    gate_k<<<wave_blocks, 256, 0, stream>>>(xb0, gw, gdv, gsv);
    coef_k<<<edge_blocks, 256, 0, stream>>>(csr, edst, gdv, gsv, d, gb, 0, yw, nw, coef);
    agg_k<<<wave_blocks, 256, 0, stream>>>(xb0, raw, rowptr, csr, coef,
                                           (float*)nullptr, xb1);
    // layer 1: gathers from xb1, writes fp32 in-place into raw
    // (safe: each wave reads only raw[nid] before writing raw[nid])
    gate_k<<<wave_blocks, 256, 0, stream>>>(xb1, gw + 256, gdv, gsv);
    coef_k<<<edge_blocks, 256, 0, stream>>>(csr, edst, gdv, gsv, d, gb, 1, yw, nw, coef);
    agg_k<<<wave_blocks, 256, 0, stream>>>(xb1, raw, rowptr, csr, coef,
                                           raw, (unsigned short*)nullptr);

    // t2 + log_softmax
    out_k<<<(N_NODES + 63) / 64, 256, 0, stream>>>(raw, t2_w, t2_b, outp);
}

// Round 5
// 449.848 us; speedup vs baseline: 2.2092x; 1.0118x over previous
//
#include <hip/hip_runtime.h>
#include <math.h>

#define N_NODES 50000
#define N_EDGES 800000
#define IN_DIM  512
#define HID     128
#define OUT_DIM 64
#define EPS     0.3f

#define SCAN_BLOCKS 49   // ceil(50000 / 1024)

typedef __attribute__((ext_vector_type(8))) short bf16x8;
typedef __attribute__((ext_vector_type(4))) float f32x4;

__device__ __forceinline__ float fast_tanh(float x) {
    // tanh(x) = 1 - 2/(exp(2x)+1); saturates correctly at +/-inf
    return 1.0f - 2.0f / (__expf(2.0f * x) + 1.0f);
}

__device__ __forceinline__ unsigned cvt_bf16_u(float f) {
    // round-to-nearest-even fp32 -> bf16 (bits in low 16)
    unsigned u = __float_as_uint(f);
    return (u + 0x7fffu + ((u >> 16) & 1u)) >> 16;
}
__device__ __forceinline__ float bf_lo(unsigned u) { return __uint_as_float(u << 16); }
__device__ __forceinline__ float bf_hi(unsigned u) { return __uint_as_float(u & 0xffff0000u); }

// ---------------- CSR build ----------------

__global__ void hist_k(const int* __restrict__ dst, int* __restrict__ deg) {
    int e = blockIdx.x * blockDim.x + threadIdx.x;
    if (e < N_EDGES) atomicAdd(&deg[dst[e]], 1);
}

// 49 blocks x 256 threads x 4 elems: per-block degree sums
__global__ void partial_k(const int* __restrict__ deg, int* __restrict__ partials) {
    int base = blockIdx.x * 1024 + threadIdx.x * 4;
    int s = 0;
#pragma unroll
    for (int j = 0; j < 4; j++) if (base + j < N_NODES) s += deg[base + j];
#pragma unroll
    for (int off = 32; off; off >>= 1) s += __shfl_down(s, off);
    __shared__ int ws[4];
    int lane = threadIdx.x & 63, wv = threadIdx.x >> 6;
    if (lane == 0) ws[wv] = s;
    __syncthreads();
    if (threadIdx.x == 0) partials[blockIdx.x] = ws[0] + ws[1] + ws[2] + ws[3];
}

// exclusive scan of 49 partials (single lane; 49 adds) + rowptr[N]
__global__ void scanp_k(const int* __restrict__ partials, int* __restrict__ bofs,
                        int* __restrict__ rowptr) {
    if (threadIdx.x == 0) {
        int a = 0;
        for (int i = 0; i < SCAN_BLOCKS; i++) { bofs[i] = a; a += partials[i]; }
        rowptr[N_NODES] = a;
    }
}

// 49 blocks: block-internal exclusive scan + block offset -> rowptr/cursor
__global__ void scanw_k(const int* __restrict__ deg, const int* __restrict__ bofs,
                        int* __restrict__ rowptr, int* __restrict__ cursor) {
    int base = blockIdx.x * 1024 + threadIdx.x * 4;
    int v[4]; int s = 0;
#pragma unroll
    for (int j = 0; j < 4; j++) {
        v[j] = (base + j < N_NODES) ? deg[base + j] : 0;
        s += v[j];
    }
    int lane = threadIdx.x & 63, wv = threadIdx.x >> 6;
    int sc = s;
#pragma unroll
    for (int off = 1; off < 64; off <<= 1) {
        int t = __shfl_up(sc, off);
        if (lane >= off) sc += t;
    }
    __shared__ int wtot[4];
    if (lane == 63) wtot[wv] = sc;
    __syncthreads();
    int wof = 0;
    for (int w = 0; w < wv; w++) wof += wtot[w];
    int excl = bofs[blockIdx.x] + wof + (sc - s);
#pragma unroll
    for (int j = 0; j < 4; j++) {
        if (base + j < N_NODES) { rowptr[base + j] = excl; cursor[base + j] = excl; }
        excl += v[j];
    }
}

__global__ void fill_k(const int* __restrict__ src, const int* __restrict__ dst,
                       const int* __restrict__ yn, int* __restrict__ cursor,
                       int* __restrict__ csr, int* __restrict__ edst) {
    int e = blockIdx.x * blockDim.x + threadIdx.x;
    if (e >= N_EDGES) return;
    int dv = dst[e];
    int pos = atomicAdd(&cursor[dv], 1);
    csr[pos]  = src[e] | (yn[e] << 31);   // src < 2^17, yn packed in sign bit
    edst[pos] = dv;
}

// ---------------- bf16 conversions / packing ----------------

// h (fp32, 25.6M elems) -> hb (bf16 row-major), 8 elems/thread
__global__ void hb_k(const float* __restrict__ h, unsigned short* __restrict__ hb) {
    int t = blockIdx.x * blockDim.x + threadIdx.x;   // exactly 3.2M threads
    const float4* p = (const float4*)h + (size_t)t * 2;
    float4 v0 = p[0], v1 = p[1];
    uint4 pk;
    pk.x = cvt_bf16_u(v0.x) | (cvt_bf16_u(v0.y) << 16);
    pk.y = cvt_bf16_u(v0.z) | (cvt_bf16_u(v0.w) << 16);
    pk.z = cvt_bf16_u(v1.x) | (cvt_bf16_u(v1.y) << 16);
    pk.w = cvt_bf16_u(v1.z) | (cvt_bf16_u(v1.w) << 16);
    *(uint4*)&hb[(size_t)t * 8] = pk;
}

// W[128][512] -> wb packed in MFMA B-fragment order: chunk t = (ks*8+ct)*64+lane
// holds W[ct*16 + (lane&15)][ks*32 + (lane>>4)*8 + j], j=0..7
__global__ void wb_k(const float* __restrict__ w, unsigned short* __restrict__ wb) {
    int t = blockIdx.x * blockDim.x + threadIdx.x;   // 8192 threads
    if (t >= 8192) return;
    int lane = t & 63;
    int ct   = (t >> 6) & 7;
    int ks   = t >> 9;
    int row  = ct * 16 + (lane & 15);
    int kb   = ks * 32 + (lane >> 4) * 8;
    const float* p = &w[(size_t)row * IN_DIM + kb];
    float4 v0 = *(const float4*)p, v1 = *(const float4*)(p + 4);
    uint4 pk;
    pk.x = cvt_bf16_u(v0.x) | (cvt_bf16_u(v0.y) << 16);
    pk.y = cvt_bf16_u(v0.z) | (cvt_bf16_u(v0.w) << 16);
    pk.z = cvt_bf16_u(v1.x) | (cvt_bf16_u(v1.y) << 16);
    pk.w = cvt_bf16_u(v1.z) | (cvt_bf16_u(v1.w) << 16);
    *(uint4*)&wb[(size_t)t * 8] = pk;
}

// ---------------- t1 v2 (LDS-free bf16 MFMA): relu(h @ t1_w^T + b) ----------------
// One wave owns 16 rows x all 128 cols. Per K-step (32): 1 A-frag load from hb,
// 8 B-frag loads from wb (fragment-packed, L1/L2-resident), 8 MFMAs.
// No LDS, no barriers -> waves free-run and hide HBM latency.
// C/D layout: col = lane&15, row = (lane>>4)*4 + reg (verified path from R3).

__launch_bounds__(256)
__global__ void t1_k(const unsigned short* __restrict__ hb,
                     const unsigned short* __restrict__ wb,
                     const float* __restrict__ bias, float* __restrict__ out,
                     unsigned short* __restrict__ outb) {
    int tid  = threadIdx.x;
    int lane = tid & 63;
    int wv   = tid >> 6;
    int l15  = lane & 15;
    int quad = lane >> 4;
    int rowb = blockIdx.x * 64 + wv * 16;     // wave's 16 rows
    int arow = rowb + l15;
    if (arow >= N_NODES) arow = N_NODES - 1;  // clamp: stores are guarded

    const unsigned short* ap = &hb[(size_t)arow * IN_DIM + quad * 8];
    const unsigned short* bp = &wb[(size_t)lane * 8];

    f32x4 acc[8];
#pragma unroll
    for (int ct = 0; ct < 8; ct++) acc[ct] = (f32x4){0.f, 0.f, 0.f, 0.f};

#pragma unroll 2
    for (int ks = 0; ks < 16; ++ks) {
        bf16x8 af = *(const bf16x8*)(ap + ks * 32);
#pragma unroll
        for (int ct = 0; ct < 8; ++ct) {
            bf16x8 bf = *(const bf16x8*)(bp + (size_t)(ks * 8 + ct) * 512);
            acc[ct] = __builtin_amdgcn_mfma_f32_16x16x32_bf16(af, bf, acc[ct], 0, 0, 0);
        }
    }

#pragma unroll
    for (int ct = 0; ct < 8; ++ct) {
        int o = ct * 16 + l15;
        float b = bias[o];
#pragma unroll
        for (int r = 0; r < 4; ++r) {
            int node = rowb + quad * 4 + r;
            if (node < N_NODES) {
                float v = acc[ct][r] + b;
                v = v > 0.f ? v : 0.f;
                out[(size_t)node * HID + o]  = v;
                outb[(size_t)node * HID + o] = (unsigned short)cvt_bf16_u(v);
            }
        }
    }
}

// ---------------- gate dots from bf16 x: gd[n], gs[n] ----------------

__global__ void gate_k(const unsigned short* __restrict__ xb, const float* __restrict__ gw,
                       float* __restrict__ gd, float* __restrict__ gs) {
    int t = blockIdx.x * blockDim.x + threadIdx.x;
    int nid = t >> 6, lane = t & 63;
    if (nid >= N_NODES) return;
    unsigned u = *(const unsigned*)&xb[(size_t)nid * HID + lane * 2];
    float a0 = bf_lo(u), a1 = bf_hi(u);
    float2 wd = *(const float2*)&gw[lane * 2];
    float2 ws = *(const float2*)&gw[128 + lane * 2];
    float pd = a0 * wd.x + a1 * wd.y;
    float ps = a0 * ws.x + a1 * ws.y;
#pragma unroll
    for (int off = 32; off; off >>= 1) {
        pd += __shfl_down(pd, off);
        ps += __shfl_down(ps, off);
    }
    if (lane == 0) { gd[nid] = pd; gs[nid] = ps; }
}

// ---------------- per-edge coefficient (CSR order) ----------------

__global__ void coef_k(const int* __restrict__ csr, const int* __restrict__ edst,
                       const float* __restrict__ gd, const float* __restrict__ gs,
                       const float* __restrict__ d, const float* __restrict__ gb, int layer,
                       const float* __restrict__ yw, const float* __restrict__ nw,
                       float* __restrict__ coef) {
    int e = blockIdx.x * blockDim.x + threadIdx.x;
    if (e >= N_EDGES) return;
    int p = csr[e];
    int s = p & 0x7fffffff;
    int dn = edst[e];
    float ty  = fast_tanh(yw[0]);
    float tno = fast_tanh(nw[0]);
    float ynt = (p < 0) ? ty : tno;
    float g = fast_tanh(gd[dn] + gs[s] + gb[layer]);
    coef[e] = (g + ynt) * 0.5f * d[dn] * d[s];
}

// ---------------- aggregation: one wave per dst node, 4 edges/trip ----------------
// lanes grouped 16/edge; each lane holds 8 elems (16B bf16 gather); xor-fold at end.

__global__ void agg_k(const unsigned short* __restrict__ xb, const float* __restrict__ raw,
                      const int* __restrict__ rowptr, const int* __restrict__ csr,
                      const float* __restrict__ coef,
                      float* __restrict__ outf, unsigned short* __restrict__ outb) {
    int t = blockIdx.x * blockDim.x + threadIdx.x;
    int nid = t >> 6, lane = t & 63;
    if (nid >= N_NODES) return;
    int l15 = lane & 15, eg = lane >> 4;
    float acc[8];
    if (lane < 16) {
        const float4* rr = (const float4*)&raw[(size_t)nid * HID + l15 * 8];
        float4 r0 = rr[0], r1 = rr[1];
        acc[0] = EPS * r0.x; acc[1] = EPS * r0.y; acc[2] = EPS * r0.z; acc[3] = EPS * r0.w;
        acc[4] = EPS * r1.x; acc[5] = EPS * r1.y; acc[6] = EPS * r1.z; acc[7] = EPS * r1.w;
    } else {
#pragma unroll
        for (int j = 0; j < 8; j++) acc[j] = 0.f;
    }
    int e0 = rowptr[nid], e1 = rowptr[nid + 1];
    for (int eb = e0; eb < e1; eb += 4) {
        int e = eb + eg;
        if (e < e1) {
            int p = csr[e];
            int s = p & 0x7fffffff;
            float cf = coef[e];
            uint4 v = *(const uint4*)&xb[(size_t)s * HID + l15 * 8];
            acc[0] += cf * bf_lo(v.x); acc[1] += cf * bf_hi(v.x);
            acc[2] += cf * bf_lo(v.y); acc[3] += cf * bf_hi(v.y);
            acc[4] += cf * bf_lo(v.z); acc[5] += cf * bf_hi(v.z);
            acc[6] += cf * bf_lo(v.w); acc[7] += cf * bf_hi(v.w);
        }
    }
#pragma unroll
    for (int j = 0; j < 8; j++) acc[j] += __shfl_xor(acc[j], 32);
#pragma unroll
    for (int j = 0; j < 8; j++) acc[j] += __shfl_xor(acc[j], 16);
    if (lane < 16) {
        if (outf) {
            float4* of = (float4*)&outf[(size_t)nid * HID + l15 * 8];
            of[0] = make_float4(acc[0], acc[1], acc[2], acc[3]);
            of[1] = make_float4(acc[4], acc[5], acc[6], acc[7]);
        }
        if (outb) {
            uint4 pk;
            pk.x = cvt_bf16_u(acc[0]) | (cvt_bf16_u(acc[1]) << 16);
            pk.y = cvt_bf16_u(acc[2]) | (cvt_bf16_u(acc[3]) << 16);
            pk.z = cvt_bf16_u(acc[4]) | (cvt_bf16_u(acc[5]) << 16);
            pk.w = cvt_bf16_u(acc[6]) | (cvt_bf16_u(acc[7]) << 16);
            *(uint4*)&outb[(size_t)nid * HID + l15 * 8] = pk;
        }
    }
}

// ---------------- t2 + log_softmax: 64-node tile per block ----------------

__launch_bounds__(256)
__global__ void out_k(const float* __restrict__ x, const float* __restrict__ w,
                      const float* __restrict__ bias, float* __restrict__ out) {
    __shared__ float As[64][132];   // 64 nodes x 128 k
    __shared__ float Bs[64][132];   // 64 outs  x 128 k
    int tid = threadIdx.x;
    int n0  = blockIdx.x * 64;
#pragma unroll
    for (int j = 0; j < 8; j++) {
        int f4 = tid + j * 256;
        int r = f4 >> 5, c = (f4 & 31) * 4;
        float4 v = make_float4(0.f, 0.f, 0.f, 0.f);
        int gr = n0 + r;
        if (gr < N_NODES) v = *(const float4*)&x[gr * HID + c];
        *(float4*)&As[r][c] = v;
        *(float4*)&Bs[r][c] = *(const float4*)&w[r * HID + c];
    }
    __syncthreads();
    int tn = tid >> 4, to = tid & 15;
    float acc[4][4];
#pragma unroll
    for (int i = 0; i < 4; i++)
#pragma unroll
        for (int j = 0; j < 4; j++) acc[i][j] = 0.0f;
    // unroll capped at 2: full unroll was the VGPR=256 spill (R1)
#pragma unroll 2
    for (int k = 0; k < HID; k += 4) {
        float4 av[4], bv[4];
#pragma unroll
        for (int i = 0; i < 4; i++) av[i] = *(const float4*)&As[tn + 16 * i][k];
#pragma unroll
        for (int j = 0; j < 4; j++) bv[j] = *(const float4*)&Bs[to + 16 * j][k];
#pragma unroll
        for (int i = 0; i < 4; i++)
#pragma unroll
            for (int j = 0; j < 4; j++) {
                acc[i][j] += av[i].x * bv[j].x;
                acc[i][j] += av[i].y * bv[j].y;
                acc[i][j] += av[i].z * bv[j].z;
                acc[i][j] += av[i].w * bv[j].w;
            }
    }
    float bj[4];
#pragma unroll
    for (int j = 0; j < 4; j++) bj[j] = bias[to + 16 * j];
#pragma unroll
    for (int i = 0; i < 4; i++) {
        float v[4];
        float m = -1e30f;
#pragma unroll
        for (int j = 0; j < 4; j++) { v[j] = acc[i][j] + bj[j]; m = fmaxf(m, v[j]); }
#pragma unroll
        for (int s = 1; s < 16; s <<= 1) m = fmaxf(m, __shfl_xor(m, s));
        float sum = 0.f;
#pragma unroll
        for (int j = 0; j < 4; j++) sum += __expf(v[j] - m);
#pragma unroll
        for (int s = 1; s < 16; s <<= 1) sum += __shfl_xor(sum, s);
        float lse = m + __logf(sum);
        int r = n0 + tn + 16 * i;
        if (r < N_NODES) {
#pragma unroll
            for (int j = 0; j < 4; j++) out[r * OUT_DIM + to + 16 * j] = v[j] - lse;
        }
    }
}

// ---------------- launcher ----------------

extern "C" void kernel_launch(void* const* d_in, const int* in_sizes, int n_in,
                              void* d_out, int out_size, void* d_ws, size_t ws_size,
                              hipStream_t stream) {
    const float* h    = (const float*)d_in[0];
    const float* d    = (const float*)d_in[1];
    const float* t1_w = (const float*)d_in[2];
    const float* t1_b = (const float*)d_in[3];
    const float* gw   = (const float*)d_in[4];   // [2][256]
    const float* gb   = (const float*)d_in[5];   // [2]
    const float* t2_w = (const float*)d_in[6];   // [64][128]
    const float* t2_b = (const float*)d_in[7];
    const float* yw   = (const float*)d_in[8];
    const float* nw   = (const float*)d_in[9];
    const int* src    = (const int*)d_in[10];
    const int* dst    = (const int*)d_in[11];
    const int* yn     = (const int*)d_in[12];
    float* outp = (float*)d_out;

    char* ws = (char*)d_ws;
    size_t off = 0;
    auto alloc = [&](size_t bytes) {
        void* p = ws + off;
        off = (off + bytes + 255) & ~(size_t)255;
        return p;
    };
    float*          raw = (float*)alloc((size_t)N_NODES * HID * 4);
    unsigned short* xb0 = (unsigned short*)alloc((size_t)N_NODES * HID * 2);
    unsigned short* hb  = (unsigned short*)alloc((size_t)N_NODES * IN_DIM * 2);  // 51.2 MB
    unsigned short* wb  = (unsigned short*)alloc((size_t)8192 * 8 * 2);
    float* gdv    = (float*)alloc((size_t)N_NODES * 4);
    float* gsv    = (float*)alloc((size_t)N_NODES * 4);
    int*   deg    = (int*)alloc((size_t)N_NODES * 4);
    int*   rowptr = (int*)alloc((size_t)(N_NODES + 1) * 4);
    int*   cursor = (int*)alloc((size_t)N_NODES * 4);
    int*   csr    = (int*)alloc((size_t)N_EDGES * 4);
    int*   edst   = (int*)alloc((size_t)N_EDGES * 4);
    int*   partials = (int*)alloc(64 * 4);
    int*   bofs     = (int*)alloc(64 * 4);
    // hb is dead after t1_k -> alias xb1 and coef into its region (stream-ordered)
    unsigned short* xb1  = hb;                                           // 12.8 MB
    float*          coef = (float*)((char*)hb + ((size_t)N_NODES * HID * 2 + 255 & ~(size_t)255));
    (void)ws_size; (void)n_in; (void)in_sizes; (void)out_size;

    // CSR build (parallel scan: 49-block partials -> 1-wave scan -> 49-block write)
    hipMemsetAsync(deg, 0, (size_t)N_NODES * 4, stream);
    hist_k<<<(N_EDGES + 255) / 256, 256, 0, stream>>>(dst, deg);
    partial_k<<<SCAN_BLOCKS, 256, 0, stream>>>(deg, partials);
    scanp_k<<<1, 64, 0, stream>>>(partials, bofs, rowptr);
    scanw_k<<<SCAN_BLOCKS, 256, 0, stream>>>(deg, bofs, rowptr, cursor);
    fill_k<<<(N_EDGES + 255) / 256, 256, 0, stream>>>(src, dst, yn, cursor, csr, edst);

    // bf16 conversions
    hb_k<<<(N_NODES * IN_DIM / 8) / 256, 256, 0, stream>>>(h, hb);
    wb_k<<<32, 256, 0, stream>>>(t1_w, wb);

    // t1: raw(fp32) + xb0(bf16) = relu(h @ t1_w^T + b)  [LDS-free bf16 MFMA]
    t1_k<<<(N_NODES + 63) / 64, 256, 0, stream>>>(hb, wb, t1_b, raw, xb0);

    int wave_blocks = (N_NODES * 64 + 255) / 256;   // one wave per node
    int edge_blocks = (N_EDGES + 255) / 256;

    // layer 0: gathers from xb0, writes xb1 (bf16 only)
    gate_k<<<wave_blocks, 256, 0, stream>>>(xb0, gw, gdv, gsv);
    coef_k<<<edge_blocks, 256, 0, stream>>>(csr, edst, gdv, gsv, d, gb, 0, yw, nw, coef);
    agg_k<<<wave_blocks, 256, 0, stream>>>(xb0, raw, rowptr, csr, coef,
                                           (float*)nullptr, xb1);
    // layer 1: gathers from xb1, writes fp32 in-place into raw
    // (safe: each wave reads only raw[nid] before writing raw[nid])
    gate_k<<<wave_blocks, 256, 0, stream>>>(xb1, gw + 256, gdv, gsv);
    coef_k<<<edge_blocks, 256, 0, stream>>>(csr, edst, gdv, gsv, d, gb, 1, yw, nw, coef);
    agg_k<<<wave_blocks, 256, 0, stream>>>(xb1, raw, rowptr, csr, coef,
                                           raw, (unsigned short*)nullptr);

    // t2 + log_softmax
    out_k<<<(N_NODES + 63) / 64, 256, 0, stream>>>(raw, t2_w, t2_b, outp);
}

// Round 7
// 419.168 us; speedup vs baseline: 2.3709x; 1.0732x over previous
//
#include <hip/hip_runtime.h>
#include <math.h>

#define N_NODES 50000
#define N_EDGES 800000
#define IN_DIM  512
#define HID     128
#define OUT_DIM 64
#define EPS     0.3f

#define SCAN_BLOCKS 49   // ceil(50000 / 1024)

typedef __attribute__((ext_vector_type(8))) short bf16x8;
typedef __attribute__((ext_vector_type(4))) float f32x4;

__device__ __forceinline__ float fast_tanh(float x) {
    // tanh(x) = 1 - 2/(exp(2x)+1); saturates correctly at +/-inf
    return 1.0f - 2.0f / (__expf(2.0f * x) + 1.0f);
}

__device__ __forceinline__ unsigned cvt_bf16_u(float f) {
    // round-to-nearest-even fp32 -> bf16 (bits in low 16)
    unsigned u = __float_as_uint(f);
    return (u + 0x7fffu + ((u >> 16) & 1u)) >> 16;
}
__device__ __forceinline__ float bf_lo(unsigned u) { return __uint_as_float(u << 16); }
__device__ __forceinline__ float bf_hi(unsigned u) { return __uint_as_float(u & 0xffff0000u); }

// ---------------- CSR build ----------------

__global__ void hist_k(const int* __restrict__ dst, int* __restrict__ deg) {
    int e = blockIdx.x * blockDim.x + threadIdx.x;
    if (e < N_EDGES) atomicAdd(&deg[dst[e]], 1);
}

// 49 blocks x 256 threads x 4 elems: per-block degree sums
__global__ void partial_k(const int* __restrict__ deg, int* __restrict__ partials) {
    int base = blockIdx.x * 1024 + threadIdx.x * 4;
    int s = 0;
#pragma unroll
    for (int j = 0; j < 4; j++) if (base + j < N_NODES) s += deg[base + j];
#pragma unroll
    for (int off = 32; off; off >>= 1) s += __shfl_down(s, off);
    __shared__ int ws[4];
    int lane = threadIdx.x & 63, wv = threadIdx.x >> 6;
    if (lane == 0) ws[wv] = s;
    __syncthreads();
    if (threadIdx.x == 0) partials[blockIdx.x] = ws[0] + ws[1] + ws[2] + ws[3];
}

// exclusive scan of 49 partials (single lane; 49 adds) + rowptr[N]
__global__ void scanp_k(const int* __restrict__ partials, int* __restrict__ bofs,
                        int* __restrict__ rowptr) {
    if (threadIdx.x == 0) {
        int a = 0;
        for (int i = 0; i < SCAN_BLOCKS; i++) { bofs[i] = a; a += partials[i]; }
        rowptr[N_NODES] = a;
    }
}

// 49 blocks: block-internal exclusive scan + block offset -> rowptr/cursor
__global__ void scanw_k(const int* __restrict__ deg, const int* __restrict__ bofs,
                        int* __restrict__ rowptr, int* __restrict__ cursor) {
    int base = blockIdx.x * 1024 + threadIdx.x * 4;
    int v[4]; int s = 0;
#pragma unroll
    for (int j = 0; j < 4; j++) {
        v[j] = (base + j < N_NODES) ? deg[base + j] : 0;
        s += v[j];
    }
    int lane = threadIdx.x & 63, wv = threadIdx.x >> 6;
    int sc = s;
#pragma unroll
    for (int off = 1; off < 64; off <<= 1) {
        int t = __shfl_up(sc, off);
        if (lane >= off) sc += t;
    }
    __shared__ int wtot[4];
    if (lane == 63) wtot[wv] = sc;
    __syncthreads();
    int wof = 0;
    for (int w = 0; w < wv; w++) wof += wtot[w];
    int excl = bofs[blockIdx.x] + wof + (sc - s);
#pragma unroll
    for (int j = 0; j < 4; j++) {
        if (base + j < N_NODES) { rowptr[base + j] = excl; cursor[base + j] = excl; }
        excl += v[j];
    }
}

// single 4B store per edge
__global__ void fill_k(const int* __restrict__ src, const int* __restrict__ dst,
                       const int* __restrict__ yn, int* __restrict__ cursor,
                       int* __restrict__ csr) {
    int e = blockIdx.x * blockDim.x + threadIdx.x;
    if (e >= N_EDGES) return;
    int pos = atomicAdd(&cursor[dst[e]], 1);
    csr[pos] = src[e] | (yn[e] << 31);   // src < 2^17, yn packed in sign bit
}

// ---------------- W pack: MFMA B-fragment order ----------------
// chunk t = (ks*8+ct)*64+lane holds W[ct*16+(lane&15)][ks*32+(lane>>4)*8 + j]

__global__ void wb_k(const float* __restrict__ w, unsigned short* __restrict__ wb) {
    int t = blockIdx.x * blockDim.x + threadIdx.x;   // 8192 threads
    if (t >= 8192) return;
    int lane = t & 63;
    int ct   = (t >> 6) & 7;
    int ks   = t >> 9;
    int row  = ct * 16 + (lane & 15);
    int kb   = ks * 32 + (lane >> 4) * 8;
    const float* p = &w[(size_t)row * IN_DIM + kb];
    float4 v0 = *(const float4*)p, v1 = *(const float4*)(p + 4);
    uint4 pk;
    pk.x = cvt_bf16_u(v0.x) | (cvt_bf16_u(v0.y) << 16);
    pk.y = cvt_bf16_u(v0.z) | (cvt_bf16_u(v0.w) << 16);
    pk.z = cvt_bf16_u(v1.x) | (cvt_bf16_u(v1.y) << 16);
    pk.w = cvt_bf16_u(v1.z) | (cvt_bf16_u(v1.w) << 16);
    *(uint4*)&wb[(size_t)t * 8] = pk;
}

// ---------------- t1 (LDS-free bf16 MFMA) + fused layer-0 gate ----------------
// One wave owns 16 rows x all 128 cols. Reads fp32 h directly, cvt in-reg.
// C/D layout: col = lane&15 (+16*ct), row = (lane>>4)*4 + reg.

__launch_bounds__(256)
__global__ void t1_k(const float* __restrict__ h, const unsigned short* __restrict__ wb,
                     const float* __restrict__ bias, const float* __restrict__ gw0,
                     unsigned short* __restrict__ xb0,
                     float* __restrict__ gd0, float* __restrict__ gs0) {
    int tid  = threadIdx.x;
    int lane = tid & 63;
    int wv   = tid >> 6;
    int l15  = lane & 15;
    int quad = lane >> 4;
    int rowb = blockIdx.x * 64 + wv * 16;     // wave's 16 rows
    int arow = rowb + l15;
    if (arow >= N_NODES) arow = N_NODES - 1;  // clamp: stores are guarded

    const float* ap = &h[(size_t)arow * IN_DIM + quad * 8];
    const unsigned short* bp = &wb[(size_t)lane * 8];

    f32x4 acc[8];
#pragma unroll
    for (int ct = 0; ct < 8; ct++) acc[ct] = (f32x4){0.f, 0.f, 0.f, 0.f};

#pragma unroll 2
    for (int ks = 0; ks < 16; ++ks) {
        float4 a0 = *(const float4*)(ap + ks * 32);
        float4 a1 = *(const float4*)(ap + ks * 32 + 4);
        bf16x8 af;
        af[0] = (short)cvt_bf16_u(a0.x); af[1] = (short)cvt_bf16_u(a0.y);
        af[2] = (short)cvt_bf16_u(a0.z); af[3] = (short)cvt_bf16_u(a0.w);
        af[4] = (short)cvt_bf16_u(a1.x); af[5] = (short)cvt_bf16_u(a1.y);
        af[6] = (short)cvt_bf16_u(a1.z); af[7] = (short)cvt_bf16_u(a1.w);
#pragma unroll
        for (int ct = 0; ct < 8; ++ct) {
            bf16x8 bf = *(const bf16x8*)(bp + (size_t)(ks * 8 + ct) * 512);
            acc[ct] = __builtin_amdgcn_mfma_f32_16x16x32_bf16(af, bf, acc[ct], 0, 0, 0);
        }
    }

    // epilogue: bias+relu (in place), store bf16
#pragma unroll
    for (int ct = 0; ct < 8; ++ct) {
        int o = ct * 16 + l15;
        float b = bias[o];
#pragma unroll
        for (int r = 0; r < 4; ++r) {
            float v = acc[ct][r] + b;
            v = v > 0.f ? v : 0.f;
            acc[ct][r] = v;
            int node = rowb + quad * 4 + r;
            if (node < N_NODES)
                xb0[(size_t)node * HID + o] = (unsigned short)cvt_bf16_u(v);
        }
    }
    // fused gate dots for layer 0: per row, pd = x.gw0[0:128], ps = x.gw0[128:256]
    float pd[4] = {0.f, 0.f, 0.f, 0.f}, ps[4] = {0.f, 0.f, 0.f, 0.f};
#pragma unroll
    for (int ct = 0; ct < 8; ++ct) {
        int o = ct * 16 + l15;
        float wd = gw0[o], wsv = gw0[128 + o];
#pragma unroll
        for (int r = 0; r < 4; ++r) { pd[r] += acc[ct][r] * wd; ps[r] += acc[ct][r] * wsv; }
    }
#pragma unroll
    for (int m = 1; m < 16; m <<= 1) {
#pragma unroll
        for (int r = 0; r < 4; ++r) {
            pd[r] += __shfl_xor(pd[r], m);
            ps[r] += __shfl_xor(ps[r], m);
        }
    }
    if (l15 == 0) {
#pragma unroll
        for (int r = 0; r < 4; ++r) {
            int node = rowb + quad * 4 + r;
            if (node < N_NODES) { gd0[node] = pd[r]; gs0[node] = ps[r]; }
        }
    }
}

// ---------------- aggregation (coef inline) + optional fused next-layer gate -----
// One wave per dst node. Batch phase: lane e computes coef for edge e0+lane.
// Gather phase: 4 edges/trip, 16 lanes/edge, coef/src broadcast via __shfl.
// NOTE: rb (residual, = original t1 output x0) is SEPARATE from xb (gather
// source) — R6's bug was collapsing them; reference keeps raw fixed across layers.

__global__ void agg_k(const unsigned short* __restrict__ xb,
                      const unsigned short* __restrict__ rb,
                      const int* __restrict__ rowptr, const int* __restrict__ csr,
                      const float* __restrict__ d,
                      const float* __restrict__ gd, const float* __restrict__ gs,
                      const float* __restrict__ gb, int layer,
                      const float* __restrict__ yw, const float* __restrict__ nw,
                      const float* __restrict__ gw_next,
                      float* __restrict__ gd_out, float* __restrict__ gs_out,
                      unsigned short* __restrict__ xb_out) {
    int t = blockIdx.x * blockDim.x + threadIdx.x;
    int nid = t >> 6, lane = t & 63;
    if (nid >= N_NODES) return;
    int l15 = lane & 15, eg = lane >> 4;
    float acc[8];
#pragma unroll
    for (int j = 0; j < 8; j++) acc[j] = 0.f;
    if (lane < 16) {
        uint4 rv = *(const uint4*)&rb[(size_t)nid * HID + l15 * 8];
        acc[0] = EPS * bf_lo(rv.x); acc[1] = EPS * bf_hi(rv.x);
        acc[2] = EPS * bf_lo(rv.y); acc[3] = EPS * bf_hi(rv.y);
        acc[4] = EPS * bf_lo(rv.z); acc[5] = EPS * bf_hi(rv.z);
        acc[6] = EPS * bf_lo(rv.w); acc[7] = EPS * bf_hi(rv.w);
    }
    float gdn = gd[nid] + gb[layer];
    float dn  = d[nid];
    float ty  = fast_tanh(yw[0]);
    float tno = fast_tanh(nw[0]);
    int e0 = rowptr[nid], e1 = rowptr[nid + 1];
    for (int b0 = e0; b0 < e1; b0 += 64) {
        int e = b0 + lane;
        float cf = 0.f; int sidx = 0;
        if (e < e1) {
            int p = csr[e];
            int s = p & 0x7fffffff;
            float ynt = (p < 0) ? ty : tno;
            cf = (fast_tanh(gdn + gs[s]) + ynt) * 0.5f * dn * d[s];
            sidx = s;
        }
        int trips = e1 - b0; if (trips > 64) trips = 64;
        for (int t4 = 0; t4 < trips; t4 += 4) {
            int idx = t4 + eg;
            float cfB = __shfl(cf, idx);
            int   sB  = __shfl(sidx, idx);
            if (idx < trips) {
                uint4 v = *(const uint4*)&xb[(size_t)sB * HID + l15 * 8];
                acc[0] += cfB * bf_lo(v.x); acc[1] += cfB * bf_hi(v.x);
                acc[2] += cfB * bf_lo(v.y); acc[3] += cfB * bf_hi(v.y);
                acc[4] += cfB * bf_lo(v.z); acc[5] += cfB * bf_hi(v.z);
                acc[6] += cfB * bf_lo(v.w); acc[7] += cfB * bf_hi(v.w);
            }
        }
    }
    // fold the 4 edge-groups: after this ALL lanes hold the full row chunk for l15
#pragma unroll
    for (int j = 0; j < 8; j++) acc[j] += __shfl_xor(acc[j], 32);
#pragma unroll
    for (int j = 0; j < 8; j++) acc[j] += __shfl_xor(acc[j], 16);
    if (lane < 16) {
        uint4 pk;
        pk.x = cvt_bf16_u(acc[0]) | (cvt_bf16_u(acc[1]) << 16);
        pk.y = cvt_bf16_u(acc[2]) | (cvt_bf16_u(acc[3]) << 16);
        pk.z = cvt_bf16_u(acc[4]) | (cvt_bf16_u(acc[5]) << 16);
        pk.w = cvt_bf16_u(acc[6]) | (cvt_bf16_u(acc[7]) << 16);
        *(uint4*)&xb_out[(size_t)nid * HID + l15 * 8] = pk;
    }
    // fused next-layer gate dots (layer 0 only)
    if (gw_next) {
        float pd = 0.f, psv = 0.f;
#pragma unroll
        for (int j = 0; j < 8; j++) {
            int o = l15 * 8 + j;
            pd  += acc[j] * gw_next[o];
            psv += acc[j] * gw_next[128 + o];
        }
#pragma unroll
        for (int m = 1; m < 16; m <<= 1) {
            pd  += __shfl_xor(pd, m);
            psv += __shfl_xor(psv, m);
        }
        if (lane == 0) { gd_out[nid] = pd; gs_out[nid] = psv; }
    }
}

// ---------------- t2 + log_softmax: 64-node tile per block (bf16 x) ----------------

__launch_bounds__(256)
__global__ void out_k(const unsigned short* __restrict__ xb, const float* __restrict__ w,
                      const float* __restrict__ bias, float* __restrict__ out) {
    __shared__ float As[64][132];   // 64 nodes x 128 k
    __shared__ float Bs[64][132];   // 64 outs  x 128 k
    int tid = threadIdx.x;
    int n0  = blockIdx.x * 64;
#pragma unroll
    for (int j = 0; j < 4; j++) {
        int c8 = tid + j * 256;          // 1024 chunks of 8 bf16
        int r = c8 >> 4, c = (c8 & 15) * 8;
        int gr = n0 + r;
        uint4 v = make_uint4(0, 0, 0, 0);
        if (gr < N_NODES) v = *(const uint4*)&xb[(size_t)gr * HID + c];
        *(float4*)&As[r][c]     = make_float4(bf_lo(v.x), bf_hi(v.x), bf_lo(v.y), bf_hi(v.y));
        *(float4*)&As[r][c + 4] = make_float4(bf_lo(v.z), bf_hi(v.z), bf_lo(v.w), bf_hi(v.w));
    }
#pragma unroll
    for (int j = 0; j < 8; j++) {
        int f4 = tid + j * 256;
        int r = f4 >> 5, c = (f4 & 31) * 4;
        *(float4*)&Bs[r][c] = *(const float4*)&w[r * HID + c];
    }
    __syncthreads();
    int tn = tid >> 4, to = tid & 15;
    float acc[4][4];
#pragma unroll
    for (int i = 0; i < 4; i++)
#pragma unroll
        for (int j = 0; j < 4; j++) acc[i][j] = 0.0f;
    // unroll capped at 2: full unroll was the VGPR=256 spill (R1)
#pragma unroll 2
    for (int k = 0; k < HID; k += 4) {
        float4 av[4], bv[4];
#pragma unroll
        for (int i = 0; i < 4; i++) av[i] = *(const float4*)&As[tn + 16 * i][k];
#pragma unroll
        for (int j = 0; j < 4; j++) bv[j] = *(const float4*)&Bs[to + 16 * j][k];
#pragma unroll
        for (int i = 0; i < 4; i++)
#pragma unroll
            for (int j = 0; j < 4; j++) {
                acc[i][j] += av[i].x * bv[j].x;
                acc[i][j] += av[i].y * bv[j].y;
                acc[i][j] += av[i].z * bv[j].z;
                acc[i][j] += av[i].w * bv[j].w;
            }
    }
    float bj[4];
#pragma unroll
    for (int j = 0; j < 4; j++) bj[j] = bias[to + 16 * j];
#pragma unroll
    for (int i = 0; i < 4; i++) {
        float v[4];
        float m = -1e30f;
#pragma unroll
        for (int j = 0; j < 4; j++) { v[j] = acc[i][j] + bj[j]; m = fmaxf(m, v[j]); }
#pragma unroll
        for (int s = 1; s < 16; s <<= 1) m = fmaxf(m, __shfl_xor(m, s));
        float sum = 0.f;
#pragma unroll
        for (int j = 0; j < 4; j++) sum += __expf(v[j] - m);
#pragma unroll
        for (int s = 1; s < 16; s <<= 1) sum += __shfl_xor(sum, s);
        float lse = m + __logf(sum);
        int r = n0 + tn + 16 * i;
        if (r < N_NODES) {
#pragma unroll
            for (int j = 0; j < 4; j++) out[r * OUT_DIM + to + 16 * j] = v[j] - lse;
        }
    }
}

// ---------------- launcher ----------------

extern "C" void kernel_launch(void* const* d_in, const int* in_sizes, int n_in,
                              void* d_out, int out_size, void* d_ws, size_t ws_size,
                              hipStream_t stream) {
    const float* h    = (const float*)d_in[0];
    const float* d    = (const float*)d_in[1];
    const float* t1_w = (const float*)d_in[2];
    const float* t1_b = (const float*)d_in[3];
    const float* gw   = (const float*)d_in[4];   // [2][256]
    const float* gb   = (const float*)d_in[5];   // [2]
    const float* t2_w = (const float*)d_in[6];   // [64][128]
    const float* t2_b = (const float*)d_in[7];
    const float* yw   = (const float*)d_in[8];
    const float* nw   = (const float*)d_in[9];
    const int* src    = (const int*)d_in[10];
    const int* dst    = (const int*)d_in[11];
    const int* yn     = (const int*)d_in[12];
    float* outp = (float*)d_out;

    char* ws = (char*)d_ws;
    size_t off = 0;
    auto alloc = [&](size_t bytes) {
        void* p = ws + off;
        off = (off + bytes + 255) & ~(size_t)255;
        return p;
    };
    unsigned short* xb0 = (unsigned short*)alloc((size_t)N_NODES * HID * 2);
    unsigned short* xb1 = (unsigned short*)alloc((size_t)N_NODES * HID * 2);
    unsigned short* xb2 = (unsigned short*)alloc((size_t)N_NODES * HID * 2);
    unsigned short* wb  = (unsigned short*)alloc((size_t)8192 * 8 * 2);
    float* gd0    = (float*)alloc((size_t)N_NODES * 4);
    float* gs0    = (float*)alloc((size_t)N_NODES * 4);
    float* gd1    = (float*)alloc((size_t)N_NODES * 4);
    float* gs1    = (float*)alloc((size_t)N_NODES * 4);
    int*   deg    = (int*)alloc((size_t)N_NODES * 4);
    int*   rowptr = (int*)alloc((size_t)(N_NODES + 1) * 4);
    int*   cursor = (int*)alloc((size_t)N_NODES * 4);
    int*   csr    = (int*)alloc((size_t)N_EDGES * 4);
    int*   partials = (int*)alloc(64 * 4);
    int*   bofs     = (int*)alloc(64 * 4);
    (void)ws_size; (void)n_in; (void)in_sizes; (void)out_size;

    // CSR build (parallel scan: 49-block partials -> 1-wave scan -> 49-block write)
    hipMemsetAsync(deg, 0, (size_t)N_NODES * 4, stream);
    hist_k<<<(N_EDGES + 255) / 256, 256, 0, stream>>>(dst, deg);
    partial_k<<<SCAN_BLOCKS, 256, 0, stream>>>(deg, partials);
    scanp_k<<<1, 64, 0, stream>>>(partials, bofs, rowptr);
    scanw_k<<<SCAN_BLOCKS, 256, 0, stream>>>(deg, bofs, rowptr, cursor);
    fill_k<<<(N_EDGES + 255) / 256, 256, 0, stream>>>(src, dst, yn, cursor, csr);

    // W pack (tiny) + t1 with fused layer-0 gate
    wb_k<<<32, 256, 0, stream>>>(t1_w, wb);
    t1_k<<<(N_NODES + 63) / 64, 256, 0, stream>>>(h, wb, t1_b, gw, xb0, gd0, gs0);

    int wave_blocks = (N_NODES * 64 + 255) / 256;   // one wave per node

    // layer 0: gather xb0, residual xb0 -> xb1, fused layer-1 gate dots
    agg_k<<<wave_blocks, 256, 0, stream>>>(xb0, xb0, rowptr, csr, d, gd0, gs0, gb, 0,
                                           yw, nw, gw + 256, gd1, gs1, xb1);
    // layer 1: gather xb1, residual xb0 (raw is FIXED across layers) -> xb2
    agg_k<<<wave_blocks, 256, 0, stream>>>(xb1, xb0, rowptr, csr, d, gd1, gs1, gb, 1,
                                           yw, nw, (const float*)nullptr,
                                           (float*)nullptr, (float*)nullptr, xb2);

    // t2 + log_softmax (bf16 x)
    out_k<<<(N_NODES + 63) / 64, 256, 0, stream>>>(xb2, t2_w, t2_b, outp);
}

// Round 8
// 388.956 us; speedup vs baseline: 2.5550x; 1.0777x over previous
//
#include <hip/hip_runtime.h>
#include <math.h>

#define N_NODES 50000
#define N_EDGES 800000
#define IN_DIM  512
#define HID     128
#define OUT_DIM 64
#define EPS     0.3f

#define SCAN_BLOCKS 49   // ceil(50000 / 1024)

typedef __attribute__((ext_vector_type(8))) short bf16x8;
typedef __attribute__((ext_vector_type(4))) float f32x4;

__device__ __forceinline__ float fast_tanh(float x) {
    // tanh(x) = 1 - 2/(exp(2x)+1); saturates correctly at +/-inf
    return 1.0f - 2.0f / (__expf(2.0f * x) + 1.0f);
}

__device__ __forceinline__ unsigned cvt_bf16_u(float f) {
    // round-to-nearest-even fp32 -> bf16 (bits in low 16)
    unsigned u = __float_as_uint(f);
    return (u + 0x7fffu + ((u >> 16) & 1u)) >> 16;
}
__device__ __forceinline__ float bf_lo(unsigned u) { return __uint_as_float(u << 16); }
__device__ __forceinline__ float bf_hi(unsigned u) { return __uint_as_float(u & 0xffff0000u); }

// ---------------- CSR build ----------------

__global__ void hist_k(const int* __restrict__ dst, int* __restrict__ deg) {
    int e = blockIdx.x * blockDim.x + threadIdx.x;
    if (e < N_EDGES) atomicAdd(&deg[dst[e]], 1);
}

// 49 blocks x 256 threads x 4 elems: per-block degree sums
__global__ void partial_k(const int* __restrict__ deg, int* __restrict__ partials) {
    int base = blockIdx.x * 1024 + threadIdx.x * 4;
    int s = 0;
#pragma unroll
    for (int j = 0; j < 4; j++) if (base + j < N_NODES) s += deg[base + j];
#pragma unroll
    for (int off = 32; off; off >>= 1) s += __shfl_down(s, off);
    __shared__ int ws[4];
    int lane = threadIdx.x & 63, wv = threadIdx.x >> 6;
    if (lane == 0) ws[wv] = s;
    __syncthreads();
    if (threadIdx.x == 0) partials[blockIdx.x] = ws[0] + ws[1] + ws[2] + ws[3];
}

// exclusive scan of 49 partials (single lane; 49 adds) + rowptr[N]
__global__ void scanp_k(const int* __restrict__ partials, int* __restrict__ bofs,
                        int* __restrict__ rowptr) {
    if (threadIdx.x == 0) {
        int a = 0;
        for (int i = 0; i < SCAN_BLOCKS; i++) { bofs[i] = a; a += partials[i]; }
        rowptr[N_NODES] = a;
    }
}

// 49 blocks: block-internal exclusive scan + block offset -> rowptr/cursor
__global__ void scanw_k(const int* __restrict__ deg, const int* __restrict__ bofs,
                        int* __restrict__ rowptr, int* __restrict__ cursor) {
    int base = blockIdx.x * 1024 + threadIdx.x * 4;
    int v[4]; int s = 0;
#pragma unroll
    for (int j = 0; j < 4; j++) {
        v[j] = (base + j < N_NODES) ? deg[base + j] : 0;
        s += v[j];
    }
    int lane = threadIdx.x & 63, wv = threadIdx.x >> 6;
    int sc = s;
#pragma unroll
    for (int off = 1; off < 64; off <<= 1) {
        int t = __shfl_up(sc, off);
        if (lane >= off) sc += t;
    }
    __shared__ int wtot[4];
    if (lane == 63) wtot[wv] = sc;
    __syncthreads();
    int wof = 0;
    for (int w = 0; w < wv; w++) wof += wtot[w];
    int excl = bofs[blockIdx.x] + wof + (sc - s);
#pragma unroll
    for (int j = 0; j < 4; j++) {
        if (base + j < N_NODES) { rowptr[base + j] = excl; cursor[base + j] = excl; }
        excl += v[j];
    }
}

// single 4B store per edge
__global__ void fill_k(const int* __restrict__ src, const int* __restrict__ dst,
                       const int* __restrict__ yn, int* __restrict__ cursor,
                       int* __restrict__ csr) {
    int e = blockIdx.x * blockDim.x + threadIdx.x;
    if (e >= N_EDGES) return;
    int pos = atomicAdd(&cursor[dst[e]], 1);
    csr[pos] = src[e] | (yn[e] << 31);   // src < 2^17, yn packed in sign bit
}

// ---------------- W pack: MFMA B-fragment order ----------------
// chunk t = (ks*8+ct)*64+lane holds W[ct*16+(lane&15)][ks*32+(lane>>4)*8 + j]

__global__ void wb_k(const float* __restrict__ w, unsigned short* __restrict__ wb) {
    int t = blockIdx.x * blockDim.x + threadIdx.x;   // 8192 threads
    if (t >= 8192) return;
    int lane = t & 63;
    int ct   = (t >> 6) & 7;
    int ks   = t >> 9;
    int row  = ct * 16 + (lane & 15);
    int kb   = ks * 32 + (lane >> 4) * 8;
    const float* p = &w[(size_t)row * IN_DIM + kb];
    float4 v0 = *(const float4*)p, v1 = *(const float4*)(p + 4);
    uint4 pk;
    pk.x = cvt_bf16_u(v0.x) | (cvt_bf16_u(v0.y) << 16);
    pk.y = cvt_bf16_u(v0.z) | (cvt_bf16_u(v0.w) << 16);
    pk.z = cvt_bf16_u(v1.x) | (cvt_bf16_u(v1.y) << 16);
    pk.w = cvt_bf16_u(v1.z) | (cvt_bf16_u(v1.w) << 16);
    *(uint4*)&wb[(size_t)t * 8] = pk;
}

// ---------------- t1 (K-split-4 bf16 MFMA) + fused layer-0 gate ----------------
// R7 t1 was latency-bound: 3125 waves (12/CU), 16-step serial chains, all pipes
// <12% busy. Now: block = 16 rows, its 4 waves each cover K/4 (4 MFMA steps),
// partial accs tree-merged via LDS (2 barriers/block). Wave count 4x -> 32/CU
// resident; per-wave chain 4x shorter.
// C/D layout: col = lane&15 (+16*ct), row = (lane>>4)*4 + reg.

__launch_bounds__(256)
__global__ void t1_k(const float* __restrict__ h, const unsigned short* __restrict__ wb,
                     const float* __restrict__ bias, const float* __restrict__ gw0,
                     unsigned short* __restrict__ xb0,
                     float* __restrict__ gd0, float* __restrict__ gs0) {
    // stride 34 floats: lane-to-lane = 34 dwords -> 2-way bank aliasing on
    // float2 access (free per m136); 2 buffers x 64 lanes x 34 = 17 KB
    __shared__ float red[2][64][34];
    int tid  = threadIdx.x;
    int lane = tid & 63;
    int wv   = tid >> 6;           // wave's K quarter
    int l15  = lane & 15;
    int quad = lane >> 4;
    int rowb = blockIdx.x * 16;    // block's 16 rows (50000 = 3125*16, no tail)
    int arow = rowb + l15;

    const float* ap = &h[(size_t)arow * IN_DIM + wv * 128 + quad * 8];
    const unsigned short* bp = &wb[(size_t)lane * 8];

    f32x4 acc[8];
#pragma unroll
    for (int ct = 0; ct < 8; ct++) acc[ct] = (f32x4){0.f, 0.f, 0.f, 0.f};

#pragma unroll
    for (int ks4 = 0; ks4 < 4; ++ks4) {
        int ks = wv * 4 + ks4;
        float4 a0 = *(const float4*)(ap + ks4 * 32);
        float4 a1 = *(const float4*)(ap + ks4 * 32 + 4);
        bf16x8 af;
        af[0] = (short)cvt_bf16_u(a0.x); af[1] = (short)cvt_bf16_u(a0.y);
        af[2] = (short)cvt_bf16_u(a0.z); af[3] = (short)cvt_bf16_u(a0.w);
        af[4] = (short)cvt_bf16_u(a1.x); af[5] = (short)cvt_bf16_u(a1.y);
        af[6] = (short)cvt_bf16_u(a1.z); af[7] = (short)cvt_bf16_u(a1.w);
#pragma unroll
        for (int ct = 0; ct < 8; ++ct) {
            bf16x8 bf = *(const bf16x8*)(bp + (size_t)(ks * 8 + ct) * 512);
            acc[ct] = __builtin_amdgcn_mfma_f32_16x16x32_bf16(af, bf, acc[ct], 0, 0, 0);
        }
    }

    // ---- tree merge: (0+=2, 1+=3) then (0+=1) ----
    if (wv >= 2) {
        float* dp = red[wv - 2][lane];
#pragma unroll
        for (int ct = 0; ct < 8; ++ct) {
            *(float2*)&dp[ct * 4]     = make_float2(acc[ct][0], acc[ct][1]);
            *(float2*)&dp[ct * 4 + 2] = make_float2(acc[ct][2], acc[ct][3]);
        }
    }
    __syncthreads();
    if (wv < 2) {
        const float* sp = red[wv][lane];
#pragma unroll
        for (int ct = 0; ct < 8; ++ct) {
            float2 p0 = *(const float2*)&sp[ct * 4];
            float2 p1 = *(const float2*)&sp[ct * 4 + 2];
            acc[ct][0] += p0.x; acc[ct][1] += p0.y;
            acc[ct][2] += p1.x; acc[ct][3] += p1.y;
        }
    }
    if (wv == 1) {   // wave 1 re-writes its merged partial into red[1] (safe: only
                     // wave 1 read red[1] in phase 2; wave 0 reads it after barrier)
        float* dp = red[1][lane];
#pragma unroll
        for (int ct = 0; ct < 8; ++ct) {
            *(float2*)&dp[ct * 4]     = make_float2(acc[ct][0], acc[ct][1]);
            *(float2*)&dp[ct * 4 + 2] = make_float2(acc[ct][2], acc[ct][3]);
        }
    }
    __syncthreads();
    if (wv != 0) return;
    {
        const float* sp = red[1][lane];
#pragma unroll
        for (int ct = 0; ct < 8; ++ct) {
            float2 p0 = *(const float2*)&sp[ct * 4];
            float2 p1 = *(const float2*)&sp[ct * 4 + 2];
            acc[ct][0] += p0.x; acc[ct][1] += p0.y;
            acc[ct][2] += p1.x; acc[ct][3] += p1.y;
        }
    }

    // epilogue (wave 0 only): bias+relu, store bf16
#pragma unroll
    for (int ct = 0; ct < 8; ++ct) {
        int o = ct * 16 + l15;
        float b = bias[o];
#pragma unroll
        for (int r = 0; r < 4; ++r) {
            float v = acc[ct][r] + b;
            v = v > 0.f ? v : 0.f;
            acc[ct][r] = v;
            int node = rowb + quad * 4 + r;
            xb0[(size_t)node * HID + o] = (unsigned short)cvt_bf16_u(v);
        }
    }
    // fused gate dots for layer 0
    float pd[4] = {0.f, 0.f, 0.f, 0.f}, ps[4] = {0.f, 0.f, 0.f, 0.f};
#pragma unroll
    for (int ct = 0; ct < 8; ++ct) {
        int o = ct * 16 + l15;
        float wd = gw0[o], wsv = gw0[128 + o];
#pragma unroll
        for (int r = 0; r < 4; ++r) { pd[r] += acc[ct][r] * wd; ps[r] += acc[ct][r] * wsv; }
    }
#pragma unroll
    for (int m = 1; m < 16; m <<= 1) {
#pragma unroll
        for (int r = 0; r < 4; ++r) {
            pd[r] += __shfl_xor(pd[r], m);
            ps[r] += __shfl_xor(ps[r], m);
        }
    }
    if (l15 == 0) {
#pragma unroll
        for (int r = 0; r < 4; ++r) {
            int node = rowb + quad * 4 + r;
            gd0[node] = pd[r]; gs0[node] = ps[r];
        }
    }
}

// ---------------- aggregation (coef inline) + optional fused next-layer gate -----
// One wave per dst node. Batch phase: lane e computes coef for edge e0+lane.
// Gather phase: 4 edges/trip, 16 lanes/edge, coef/src broadcast via __shfl.
// rb (residual = original t1 output x0) is SEPARATE from xb (gather source).

__global__ void agg_k(const unsigned short* __restrict__ xb,
                      const unsigned short* __restrict__ rb,
                      const int* __restrict__ rowptr, const int* __restrict__ csr,
                      const float* __restrict__ d,
                      const float* __restrict__ gd, const float* __restrict__ gs,
                      const float* __restrict__ gb, int layer,
                      const float* __restrict__ yw, const float* __restrict__ nw,
                      const float* __restrict__ gw_next,
                      float* __restrict__ gd_out, float* __restrict__ gs_out,
                      unsigned short* __restrict__ xb_out) {
    int t = blockIdx.x * blockDim.x + threadIdx.x;
    int nid = t >> 6, lane = t & 63;
    if (nid >= N_NODES) return;
    int l15 = lane & 15, eg = lane >> 4;
    float acc[8];
#pragma unroll
    for (int j = 0; j < 8; j++) acc[j] = 0.f;
    if (lane < 16) {
        uint4 rv = *(const uint4*)&rb[(size_t)nid * HID + l15 * 8];
        acc[0] = EPS * bf_lo(rv.x); acc[1] = EPS * bf_hi(rv.x);
        acc[2] = EPS * bf_lo(rv.y); acc[3] = EPS * bf_hi(rv.y);
        acc[4] = EPS * bf_lo(rv.z); acc[5] = EPS * bf_hi(rv.z);
        acc[6] = EPS * bf_lo(rv.w); acc[7] = EPS * bf_hi(rv.w);
    }
    float gdn = gd[nid] + gb[layer];
    float dn  = d[nid];
    float ty  = fast_tanh(yw[0]);
    float tno = fast_tanh(nw[0]);
    int e0 = rowptr[nid], e1 = rowptr[nid + 1];
    for (int b0 = e0; b0 < e1; b0 += 64) {
        int e = b0 + lane;
        float cf = 0.f; int sidx = 0;
        if (e < e1) {
            int p = csr[e];
            int s = p & 0x7fffffff;
            float ynt = (p < 0) ? ty : tno;
            cf = (fast_tanh(gdn + gs[s]) + ynt) * 0.5f * dn * d[s];
            sidx = s;
        }
        int trips = e1 - b0; if (trips > 64) trips = 64;
        for (int t4 = 0; t4 < trips; t4 += 4) {
            int idx = t4 + eg;
            float cfB = __shfl(cf, idx);
            int   sB  = __shfl(sidx, idx);
            if (idx < trips) {
                uint4 v = *(const uint4*)&xb[(size_t)sB * HID + l15 * 8];
                acc[0] += cfB * bf_lo(v.x); acc[1] += cfB * bf_hi(v.x);
                acc[2] += cfB * bf_lo(v.y); acc[3] += cfB * bf_hi(v.y);
                acc[4] += cfB * bf_lo(v.z); acc[5] += cfB * bf_hi(v.z);
                acc[6] += cfB * bf_lo(v.w); acc[7] += cfB * bf_hi(v.w);
            }
        }
    }
    // fold the 4 edge-groups: after this ALL lanes hold the full row chunk for l15
#pragma unroll
    for (int j = 0; j < 8; j++) acc[j] += __shfl_xor(acc[j], 32);
#pragma unroll
    for (int j = 0; j < 8; j++) acc[j] += __shfl_xor(acc[j], 16);
    if (lane < 16) {
        uint4 pk;
        pk.x = cvt_bf16_u(acc[0]) | (cvt_bf16_u(acc[1]) << 16);
        pk.y = cvt_bf16_u(acc[2]) | (cvt_bf16_u(acc[3]) << 16);
        pk.z = cvt_bf16_u(acc[4]) | (cvt_bf16_u(acc[5]) << 16);
        pk.w = cvt_bf16_u(acc[6]) | (cvt_bf16_u(acc[7]) << 16);
        *(uint4*)&xb_out[(size_t)nid * HID + l15 * 8] = pk;
    }
    // fused next-layer gate dots (layer 0 only)
    if (gw_next) {
        float pd = 0.f, psv = 0.f;
#pragma unroll
        for (int j = 0; j < 8; j++) {
            int o = l15 * 8 + j;
            pd  += acc[j] * gw_next[o];
            psv += acc[j] * gw_next[128 + o];
        }
#pragma unroll
        for (int m = 1; m < 16; m <<= 1) {
            pd  += __shfl_xor(pd, m);
            psv += __shfl_xor(psv, m);
        }
        if (lane == 0) { gd_out[nid] = pd; gs_out[nid] = psv; }
    }
}

// ---------------- t2 + log_softmax: 64-node tile per block (bf16 x) ----------------

__launch_bounds__(256)
__global__ void out_k(const unsigned short* __restrict__ xb, const float* __restrict__ w,
                      const float* __restrict__ bias, float* __restrict__ out) {
    __shared__ float As[64][132];   // 64 nodes x 128 k
    __shared__ float Bs[64][132];   // 64 outs  x 128 k
    int tid = threadIdx.x;
    int n0  = blockIdx.x * 64;
#pragma unroll
    for (int j = 0; j < 4; j++) {
        int c8 = tid + j * 256;          // 1024 chunks of 8 bf16
        int r = c8 >> 4, c = (c8 & 15) * 8;
        int gr = n0 + r;
        uint4 v = make_uint4(0, 0, 0, 0);
        if (gr < N_NODES) v = *(const uint4*)&xb[(size_t)gr * HID + c];
        *(float4*)&As[r][c]     = make_float4(bf_lo(v.x), bf_hi(v.x), bf_lo(v.y), bf_hi(v.y));
        *(float4*)&As[r][c + 4] = make_float4(bf_lo(v.z), bf_hi(v.z), bf_lo(v.w), bf_hi(v.w));
    }
#pragma unroll
    for (int j = 0; j < 8; j++) {
        int f4 = tid + j * 256;
        int r = f4 >> 5, c = (f4 & 31) * 4;
        *(float4*)&Bs[r][c] = *(const float4*)&w[r * HID + c];
    }
    __syncthreads();
    int tn = tid >> 4, to = tid & 15;
    float acc[4][4];
#pragma unroll
    for (int i = 0; i < 4; i++)
#pragma unroll
        for (int j = 0; j < 4; j++) acc[i][j] = 0.0f;
    // unroll capped at 2: full unroll was the VGPR=256 spill (R1)
#pragma unroll 2
    for (int k = 0; k < HID; k += 4) {
        float4 av[4], bv[4];
#pragma unroll
        for (int i = 0; i < 4; i++) av[i] = *(const float4*)&As[tn + 16 * i][k];
#pragma unroll
        for (int j = 0; j < 4; j++) bv[j] = *(const float4*)&Bs[to + 16 * j][k];
#pragma unroll
        for (int i = 0; i < 4; i++)
#pragma unroll
            for (int j = 0; j < 4; j++) {
                acc[i][j] += av[i].x * bv[j].x;
                acc[i][j] += av[i].y * bv[j].y;
                acc[i][j] += av[i].z * bv[j].z;
                acc[i][j] += av[i].w * bv[j].w;
            }
    }
    float bj[4];
#pragma unroll
    for (int j = 0; j < 4; j++) bj[j] = bias[to + 16 * j];
#pragma unroll
    for (int i = 0; i < 4; i++) {
        float v[4];
        float m = -1e30f;
#pragma unroll
        for (int j = 0; j < 4; j++) { v[j] = acc[i][j] + bj[j]; m = fmaxf(m, v[j]); }
#pragma unroll
        for (int s = 1; s < 16; s <<= 1) m = fmaxf(m, __shfl_xor(m, s));
        float sum = 0.f;
#pragma unroll
        for (int j = 0; j < 4; j++) sum += __expf(v[j] - m);
#pragma unroll
        for (int s = 1; s < 16; s <<= 1) sum += __shfl_xor(sum, s);
        float lse = m + __logf(sum);
        int r = n0 + tn + 16 * i;
        if (r < N_NODES) {
#pragma unroll
            for (int j = 0; j < 4; j++) out[r * OUT_DIM + to + 16 * j] = v[j] - lse;
        }
    }
}

// ---------------- launcher ----------------

extern "C" void kernel_launch(void* const* d_in, const int* in_sizes, int n_in,
                              void* d_out, int out_size, void* d_ws, size_t ws_size,
                              hipStream_t stream) {
    const float* h    = (const float*)d_in[0];
    const float* d    = (const float*)d_in[1];
    const float* t1_w = (const float*)d_in[2];
    const float* t1_b = (const float*)d_in[3];
    const float* gw   = (const float*)d_in[4];   // [2][256]
    const float* gb   = (const float*)d_in[5];   // [2]
    const float* t2_w = (const float*)d_in[6];   // [64][128]
    const float* t2_b = (const float*)d_in[7];
    const float* yw   = (const float*)d_in[8];
    const float* nw   = (const float*)d_in[9];
    const int* src    = (const int*)d_in[10];
    const int* dst    = (const int*)d_in[11];
    const int* yn     = (const int*)d_in[12];
    float* outp = (float*)d_out;

    char* ws = (char*)d_ws;
    size_t off = 0;
    auto alloc = [&](size_t bytes) {
        void* p = ws + off;
        off = (off + bytes + 255) & ~(size_t)255;
        return p;
    };
    unsigned short* xb0 = (unsigned short*)alloc((size_t)N_NODES * HID * 2);
    unsigned short* xb1 = (unsigned short*)alloc((size_t)N_NODES * HID * 2);
    unsigned short* xb2 = (unsigned short*)alloc((size_t)N_NODES * HID * 2);
    unsigned short* wb  = (unsigned short*)alloc((size_t)8192 * 8 * 2);
    float* gd0    = (float*)alloc((size_t)N_NODES * 4);
    float* gs0    = (float*)alloc((size_t)N_NODES * 4);
    float* gd1    = (float*)alloc((size_t)N_NODES * 4);
    float* gs1    = (float*)alloc((size_t)N_NODES * 4);
    int*   deg    = (int*)alloc((size_t)N_NODES * 4);
    int*   rowptr = (int*)alloc((size_t)(N_NODES + 1) * 4);
    int*   cursor = (int*)alloc((size_t)N_NODES * 4);
    int*   csr    = (int*)alloc((size_t)N_EDGES * 4);
    int*   partials = (int*)alloc(64 * 4);
    int*   bofs     = (int*)alloc(64 * 4);
    (void)ws_size; (void)n_in; (void)in_sizes; (void)out_size;

    // CSR build (parallel scan: 49-block partials -> 1-wave scan -> 49-block write)
    hipMemsetAsync(deg, 0, (size_t)N_NODES * 4, stream);
    hist_k<<<(N_EDGES + 255) / 256, 256, 0, stream>>>(dst, deg);
    partial_k<<<SCAN_BLOCKS, 256, 0, stream>>>(deg, partials);
    scanp_k<<<1, 64, 0, stream>>>(partials, bofs, rowptr);
    scanw_k<<<SCAN_BLOCKS, 256, 0, stream>>>(deg, bofs, rowptr, cursor);
    fill_k<<<(N_EDGES + 255) / 256, 256, 0, stream>>>(src, dst, yn, cursor, csr);

    // W pack (tiny) + t1 with fused layer-0 gate (K-split-4: 16 rows/block)
    wb_k<<<32, 256, 0, stream>>>(t1_w, wb);
    t1_k<<<N_NODES / 16, 256, 0, stream>>>(h, wb, t1_b, gw, xb0, gd0, gs0);

    int wave_blocks = (N_NODES * 64 + 255) / 256;   // one wave per node

    // layer 0: gather xb0, residual xb0 -> xb1, fused layer-1 gate dots
    agg_k<<<wave_blocks, 256, 0, stream>>>(xb0, xb0, rowptr, csr, d, gd0, gs0, gb, 0,
                                           yw, nw, gw + 256, gd1, gs1, xb1);
    // layer 1: gather xb1, residual xb0 (raw is FIXED across layers) -> xb2
    agg_k<<<wave_blocks, 256, 0, stream>>>(xb1, xb0, rowptr, csr, d, gd1, gs1, gb, 1,
                                           yw, nw, (const float*)nullptr,
                                           (float*)nullptr, (float*)nullptr, xb2);

    // t2 + log_softmax (bf16 x)
    out_k<<<(N_NODES + 63) / 64, 256, 0, stream>>>(xb2, t2_w, t2_b, outp);
}

// Round 9
// 385.416 us; speedup vs baseline: 2.5785x; 1.0092x over previous
//
#include <hip/hip_runtime.h>
#include <math.h>

#define N_NODES 50000
#define N_EDGES 800000
#define IN_DIM  512
#define HID     128
#define OUT_DIM 64
#define EPS     0.3f

#define SCAN_BLOCKS 49   // ceil(50000 / 1024)
#define LDS_ROW 516      // 512 + 4 dword pad -> 2-way bank aliasing (free, m136)

typedef __attribute__((ext_vector_type(8))) short bf16x8;
typedef __attribute__((ext_vector_type(4))) float f32x4;

__device__ __forceinline__ float fast_tanh(float x) {
    // tanh(x) = 1 - 2/(exp(2x)+1); saturates correctly at +/-inf
    return 1.0f - 2.0f / (__expf(2.0f * x) + 1.0f);
}

__device__ __forceinline__ unsigned cvt_bf16_u(float f) {
    // round-to-nearest-even fp32 -> bf16 (bits in low 16)
    unsigned u = __float_as_uint(f);
    return (u + 0x7fffu + ((u >> 16) & 1u)) >> 16;
}
__device__ __forceinline__ float bf_lo(unsigned u) { return __uint_as_float(u << 16); }
__device__ __forceinline__ float bf_hi(unsigned u) { return __uint_as_float(u & 0xffff0000u); }

// ---------------- CSR build ----------------

__global__ void hist_k(const int* __restrict__ dst, int* __restrict__ deg) {
    int e = blockIdx.x * blockDim.x + threadIdx.x;
    if (e < N_EDGES) atomicAdd(&deg[dst[e]], 1);
}

// 49 blocks x 256 threads x 4 elems: per-block degree sums
__global__ void partial_k(const int* __restrict__ deg, int* __restrict__ partials) {
    int base = blockIdx.x * 1024 + threadIdx.x * 4;
    int s = 0;
#pragma unroll
    for (int j = 0; j < 4; j++) if (base + j < N_NODES) s += deg[base + j];
#pragma unroll
    for (int off = 32; off; off >>= 1) s += __shfl_down(s, off);
    __shared__ int ws[4];
    int lane = threadIdx.x & 63, wv = threadIdx.x >> 6;
    if (lane == 0) ws[wv] = s;
    __syncthreads();
    if (threadIdx.x == 0) partials[blockIdx.x] = ws[0] + ws[1] + ws[2] + ws[3];
}

// exclusive scan of 49 partials (single lane; 49 adds) + rowptr[N]
__global__ void scanp_k(const int* __restrict__ partials, int* __restrict__ bofs,
                        int* __restrict__ rowptr) {
    if (threadIdx.x == 0) {
        int a = 0;
        for (int i = 0; i < SCAN_BLOCKS; i++) { bofs[i] = a; a += partials[i]; }
        rowptr[N_NODES] = a;
    }
}

// 49 blocks: block-internal exclusive scan + block offset -> rowptr/cursor
__global__ void scanw_k(const int* __restrict__ deg, const int* __restrict__ bofs,
                        int* __restrict__ rowptr, int* __restrict__ cursor) {
    int base = blockIdx.x * 1024 + threadIdx.x * 4;
    int v[4]; int s = 0;
#pragma unroll
    for (int j = 0; j < 4; j++) {
        v[j] = (base + j < N_NODES) ? deg[base + j] : 0;
        s += v[j];
    }
    int lane = threadIdx.x & 63, wv = threadIdx.x >> 6;
    int sc = s;
#pragma unroll
    for (int off = 1; off < 64; off <<= 1) {
        int t = __shfl_up(sc, off);
        if (lane >= off) sc += t;
    }
    __shared__ int wtot[4];
    if (lane == 63) wtot[wv] = sc;
    __syncthreads();
    int wof = 0;
    for (int w = 0; w < wv; w++) wof += wtot[w];
    int excl = bofs[blockIdx.x] + wof + (sc - s);
#pragma unroll
    for (int j = 0; j < 4; j++) {
        if (base + j < N_NODES) { rowptr[base + j] = excl; cursor[base + j] = excl; }
        excl += v[j];
    }
}

// single 4B store per edge
__global__ void fill_k(const int* __restrict__ src, const int* __restrict__ dst,
                       const int* __restrict__ yn, int* __restrict__ cursor,
                       int* __restrict__ csr) {
    int e = blockIdx.x * blockDim.x + threadIdx.x;
    if (e >= N_EDGES) return;
    int pos = atomicAdd(&cursor[dst[e]], 1);
    csr[pos] = src[e] | (yn[e] << 31);   // src < 2^17, yn packed in sign bit
}

// ---------------- W pack: MFMA B-fragment order ----------------
// chunk t = (ks*8+ct)*64+lane holds W[ct*16+(lane&15)][ks*32+(lane>>4)*8 + j]

__global__ void wb_k(const float* __restrict__ w, unsigned short* __restrict__ wb) {
    int t = blockIdx.x * blockDim.x + threadIdx.x;   // 8192 threads
    if (t >= 8192) return;
    int lane = t & 63;
    int ct   = (t >> 6) & 7;
    int ks   = t >> 9;
    int row  = ct * 16 + (lane & 15);
    int kb   = ks * 32 + (lane >> 4) * 8;
    const float* p = &w[(size_t)row * IN_DIM + kb];
    float4 v0 = *(const float4*)p, v1 = *(const float4*)(p + 4);
    uint4 pk;
    pk.x = cvt_bf16_u(v0.x) | (cvt_bf16_u(v0.y) << 16);
    pk.y = cvt_bf16_u(v0.z) | (cvt_bf16_u(v0.w) << 16);
    pk.z = cvt_bf16_u(v1.x) | (cvt_bf16_u(v1.y) << 16);
    pk.w = cvt_bf16_u(v1.z) | (cvt_bf16_u(v1.w) << 16);
    *(uint4*)&wb[(size_t)t * 8] = pk;
}

// ---------------- t1 v4 (global_load_lds-staged bf16 MFMA) + fused L0 gate ------
// R8 post-mortem: all direct-load variants plateau 60-76us because every A-load
// instruction is 16 rows x 64B scattered segments (request-queue bound, all pipes
// <15%). v4 stages the block's 16x512 fp32 tile via global_load_lds width=16:
// each instruction reads 1KB CONTIGUOUS (chunk = half-row, never crosses the
// padded LDS row). 4 waves then each compute 2 output col-groups over full K
// from LDS. C/D layout: col = lane&15 (+16*ct), row = (lane>>4)*4 + reg.

__launch_bounds__(256)
__global__ void t1_k(const float* __restrict__ h, const unsigned short* __restrict__ wb,
                     const float* __restrict__ bias, const float* __restrict__ gw0,
                     unsigned short* __restrict__ xb0,
                     float* __restrict__ gd0, float* __restrict__ gs0) {
    __shared__ float At[16 * LDS_ROW];      // 33 KB staged fp32 tile
    __shared__ float red[4][4][4][2];       // gate partials [wave][quad][r][pd|ps]
    int tid  = threadIdx.x;
    int lane = tid & 63;
    int wv   = tid >> 6;
    int l15  = lane & 15;
    int quad = lane >> 4;
    int rowb = blockIdx.x * 16;             // 50000 = 3125*16, no tail

    // stage: 32 chunks of 1KB (chunk c: row c>>1, half c&1), 8 per wave.
    // lds dest is wave-uniform base + lane*16 (HW) -> chunk stays inside one
    // padded row, so the pad never lands mid-chunk (m104/m108 caveat).
#pragma unroll
    for (int i = 0; i < 8; ++i) {
        int c    = wv * 8 + i;
        int row  = c >> 1, half = c & 1;
        const float* gsrc = &h[(size_t)(rowb + row) * IN_DIM + half * 256 + lane * 4];
        float* ldst = &At[row * LDS_ROW + half * 256];
        __builtin_amdgcn_global_load_lds(
            (const __attribute__((address_space(1))) unsigned int*)gsrc,
            (__attribute__((address_space(3))) unsigned int*)ldst, 16, 0, 0);
    }
    __syncthreads();

    // compute: wave wv covers output cols [wv*32, wv*32+32) = ct0, ct0+1
    int ct0 = wv * 2;
    const unsigned short* bp = &wb[(size_t)lane * 8];
    const float* arp = &At[l15 * LDS_ROW + quad * 8];
    f32x4 acc[2];
    acc[0] = (f32x4){0.f, 0.f, 0.f, 0.f};
    acc[1] = (f32x4){0.f, 0.f, 0.f, 0.f};
#pragma unroll 4
    for (int ks = 0; ks < 16; ++ks) {
        float4 a0 = *(const float4*)(arp + ks * 32);
        float4 a1 = *(const float4*)(arp + ks * 32 + 4);
        bf16x8 af;
        af[0] = (short)cvt_bf16_u(a0.x); af[1] = (short)cvt_bf16_u(a0.y);
        af[2] = (short)cvt_bf16_u(a0.z); af[3] = (short)cvt_bf16_u(a0.w);
        af[4] = (short)cvt_bf16_u(a1.x); af[5] = (short)cvt_bf16_u(a1.y);
        af[6] = (short)cvt_bf16_u(a1.z); af[7] = (short)cvt_bf16_u(a1.w);
        bf16x8 b0 = *(const bf16x8*)(bp + (size_t)(ks * 8 + ct0) * 512);
        bf16x8 b1 = *(const bf16x8*)(bp + (size_t)(ks * 8 + ct0 + 1) * 512);
        acc[0] = __builtin_amdgcn_mfma_f32_16x16x32_bf16(af, b0, acc[0], 0, 0, 0);
        acc[1] = __builtin_amdgcn_mfma_f32_16x16x32_bf16(af, b1, acc[1], 0, 0, 0);
    }

    // epilogue: bias+relu, store bf16, gate partials for this wave's 32 cols
    float pd[4] = {0.f, 0.f, 0.f, 0.f}, ps[4] = {0.f, 0.f, 0.f, 0.f};
#pragma unroll
    for (int ct = 0; ct < 2; ++ct) {
        int o = (ct0 + ct) * 16 + l15;
        float b = bias[o];
        float wd = gw0[o], wsv = gw0[128 + o];
#pragma unroll
        for (int r = 0; r < 4; ++r) {
            float v = acc[ct][r] + b;
            v = v > 0.f ? v : 0.f;
            int node = rowb + quad * 4 + r;
            xb0[(size_t)node * HID + o] = (unsigned short)cvt_bf16_u(v);
            pd[r] += v * wd; ps[r] += v * wsv;
        }
    }
    // reduce over the 16 lanes of l15
#pragma unroll
    for (int m = 1; m < 16; m <<= 1) {
#pragma unroll
        for (int r = 0; r < 4; ++r) {
            pd[r] += __shfl_xor(pd[r], m);
            ps[r] += __shfl_xor(ps[r], m);
        }
    }
    if (l15 == 0) {
#pragma unroll
        for (int r = 0; r < 4; ++r) {
            red[wv][quad][r][0] = pd[r];
            red[wv][quad][r][1] = ps[r];
        }
    }
    __syncthreads();
    // cross-wave sum: 16 rows handled by lanes 0..15 of wave 0
    if (wv == 0 && lane < 16) {
        int q = lane >> 2, r = lane & 3;
        float sd = red[0][q][r][0] + red[1][q][r][0] + red[2][q][r][0] + red[3][q][r][0];
        float ss = red[0][q][r][1] + red[1][q][r][1] + red[2][q][r][1] + red[3][q][r][1];
        gd0[rowb + lane] = sd;
        gs0[rowb + lane] = ss;
    }
}

// ---------------- aggregation (coef inline) + optional fused next-layer gate -----
// One wave per dst node. Batch phase: lane e computes coef for edge e0+lane.
// Gather phase: 4 edges/trip, 16 lanes/edge, coef/src broadcast via __shfl.
// rb (residual = original t1 output x0) is SEPARATE from xb (gather source).

__global__ void agg_k(const unsigned short* __restrict__ xb,
                      const unsigned short* __restrict__ rb,
                      const int* __restrict__ rowptr, const int* __restrict__ csr,
                      const float* __restrict__ d,
                      const float* __restrict__ gd, const float* __restrict__ gs,
                      const float* __restrict__ gb, int layer,
                      const float* __restrict__ yw, const float* __restrict__ nw,
                      const float* __restrict__ gw_next,
                      float* __restrict__ gd_out, float* __restrict__ gs_out,
                      unsigned short* __restrict__ xb_out) {
    int t = blockIdx.x * blockDim.x + threadIdx.x;
    int nid = t >> 6, lane = t & 63;
    if (nid >= N_NODES) return;
    int l15 = lane & 15, eg = lane >> 4;
    float acc[8];
#pragma unroll
    for (int j = 0; j < 8; j++) acc[j] = 0.f;
    if (lane < 16) {
        uint4 rv = *(const uint4*)&rb[(size_t)nid * HID + l15 * 8];
        acc[0] = EPS * bf_lo(rv.x); acc[1] = EPS * bf_hi(rv.x);
        acc[2] = EPS * bf_lo(rv.y); acc[3] = EPS * bf_hi(rv.y);
        acc[4] = EPS * bf_lo(rv.z); acc[5] = EPS * bf_hi(rv.z);
        acc[6] = EPS * bf_lo(rv.w); acc[7] = EPS * bf_hi(rv.w);
    }
    float gdn = gd[nid] + gb[layer];
    float dn  = d[nid];
    float ty  = fast_tanh(yw[0]);
    float tno = fast_tanh(nw[0]);
    int e0 = rowptr[nid], e1 = rowptr[nid + 1];
    for (int b0 = e0; b0 < e1; b0 += 64) {
        int e = b0 + lane;
        float cf = 0.f; int sidx = 0;
        if (e < e1) {
            int p = csr[e];
            int s = p & 0x7fffffff;
            float ynt = (p < 0) ? ty : tno;
            cf = (fast_tanh(gdn + gs[s]) + ynt) * 0.5f * dn * d[s];
            sidx = s;
        }
        int trips = e1 - b0; if (trips > 64) trips = 64;
        for (int t4 = 0; t4 < trips; t4 += 4) {
            int idx = t4 + eg;
            float cfB = __shfl(cf, idx);
            int   sB  = __shfl(sidx, idx);
            if (idx < trips) {
                uint4 v = *(const uint4*)&xb[(size_t)sB * HID + l15 * 8];
                acc[0] += cfB * bf_lo(v.x); acc[1] += cfB * bf_hi(v.x);
                acc[2] += cfB * bf_lo(v.y); acc[3] += cfB * bf_hi(v.y);
                acc[4] += cfB * bf_lo(v.z); acc[5] += cfB * bf_hi(v.z);
                acc[6] += cfB * bf_lo(v.w); acc[7] += cfB * bf_hi(v.w);
            }
        }
    }
    // fold the 4 edge-groups: after this ALL lanes hold the full row chunk for l15
#pragma unroll
    for (int j = 0; j < 8; j++) acc[j] += __shfl_xor(acc[j], 32);
#pragma unroll
    for (int j = 0; j < 8; j++) acc[j] += __shfl_xor(acc[j], 16);
    if (lane < 16) {
        uint4 pk;
        pk.x = cvt_bf16_u(acc[0]) | (cvt_bf16_u(acc[1]) << 16);
        pk.y = cvt_bf16_u(acc[2]) | (cvt_bf16_u(acc[3]) << 16);
        pk.z = cvt_bf16_u(acc[4]) | (cvt_bf16_u(acc[5]) << 16);
        pk.w = cvt_bf16_u(acc[6]) | (cvt_bf16_u(acc[7]) << 16);
        *(uint4*)&xb_out[(size_t)nid * HID + l15 * 8] = pk;
    }
    // fused next-layer gate dots (layer 0 only)
    if (gw_next) {
        float pd = 0.f, psv = 0.f;
#pragma unroll
        for (int j = 0; j < 8; j++) {
            int o = l15 * 8 + j;
            pd  += acc[j] * gw_next[o];
            psv += acc[j] * gw_next[128 + o];
        }
#pragma unroll
        for (int m = 1; m < 16; m <<= 1) {
            pd  += __shfl_xor(pd, m);
            psv += __shfl_xor(psv, m);
        }
        if (lane == 0) { gd_out[nid] = pd; gs_out[nid] = psv; }
    }
}

// ---------------- t2 + log_softmax: 64-node tile per block (bf16 x) ----------------

__launch_bounds__(256)
__global__ void out_k(const unsigned short* __restrict__ xb, const float* __restrict__ w,
                      const float* __restrict__ bias, float* __restrict__ out) {
    __shared__ float As[64][132];   // 64 nodes x 128 k
    __shared__ float Bs[64][132];   // 64 outs  x 128 k
    int tid = threadIdx.x;
    int n0  = blockIdx.x * 64;
#pragma unroll
    for (int j = 0; j < 4; j++) {
        int c8 = tid + j * 256;          // 1024 chunks of 8 bf16
        int r = c8 >> 4, c = (c8 & 15) * 8;
        int gr = n0 + r;
        uint4 v = make_uint4(0, 0, 0, 0);
        if (gr < N_NODES) v = *(const uint4*)&xb[(size_t)gr * HID + c];
        *(float4*)&As[r][c]     = make_float4(bf_lo(v.x), bf_hi(v.x), bf_lo(v.y), bf_hi(v.y));
        *(float4*)&As[r][c + 4] = make_float4(bf_lo(v.z), bf_hi(v.z), bf_lo(v.w), bf_hi(v.w));
    }
#pragma unroll
    for (int j = 0; j < 8; j++) {
        int f4 = tid + j * 256;
        int r = f4 >> 5, c = (f4 & 31) * 4;
        *(float4*)&Bs[r][c] = *(const float4*)&w[r * HID + c];
    }
    __syncthreads();
    int tn = tid >> 4, to = tid & 15;
    float acc[4][4];
#pragma unroll
    for (int i = 0; i < 4; i++)
#pragma unroll
        for (int j = 0; j < 4; j++) acc[i][j] = 0.0f;
    // unroll capped at 2: full unroll was the VGPR=256 spill (R1)
#pragma unroll 2
    for (int k = 0; k < HID; k += 4) {
        float4 av[4], bv[4];
#pragma unroll
        for (int i = 0; i < 4; i++) av[i] = *(const float4*)&As[tn + 16 * i][k];
#pragma unroll
        for (int j = 0; j < 4; j++) bv[j] = *(const float4*)&Bs[to + 16 * j][k];
#pragma unroll
        for (int i = 0; i < 4; i++)
#pragma unroll
            for (int j = 0; j < 4; j++) {
                acc[i][j] += av[i].x * bv[j].x;
                acc[i][j] += av[i].y * bv[j].y;
                acc[i][j] += av[i].z * bv[j].z;
                acc[i][j] += av[i].w * bv[j].w;
            }
    }
    float bj[4];
#pragma unroll
    for (int j = 0; j < 4; j++) bj[j] = bias[to + 16 * j];
#pragma unroll
    for (int i = 0; i < 4; i++) {
        float v[4];
        float m = -1e30f;
#pragma unroll
        for (int j = 0; j < 4; j++) { v[j] = acc[i][j] + bj[j]; m = fmaxf(m, v[j]); }
#pragma unroll
        for (int s = 1; s < 16; s <<= 1) m = fmaxf(m, __shfl_xor(m, s));
        float sum = 0.f;
#pragma unroll
        for (int j = 0; j < 4; j++) sum += __expf(v[j] - m);
#pragma unroll
        for (int s = 1; s < 16; s <<= 1) sum += __shfl_xor(sum, s);
        float lse = m + __logf(sum);
        int r = n0 + tn + 16 * i;
        if (r < N_NODES) {
#pragma unroll
            for (int j = 0; j < 4; j++) out[r * OUT_DIM + to + 16 * j] = v[j] - lse;
        }
    }
}

// ---------------- launcher ----------------

extern "C" void kernel_launch(void* const* d_in, const int* in_sizes, int n_in,
                              void* d_out, int out_size, void* d_ws, size_t ws_size,
                              hipStream_t stream) {
    const float* h    = (const float*)d_in[0];
    const float* d    = (const float*)d_in[1];
    const float* t1_w = (const float*)d_in[2];
    const float* t1_b = (const float*)d_in[3];
    const float* gw   = (const float*)d_in[4];   // [2][256]
    const float* gb   = (const float*)d_in[5];   // [2]
    const float* t2_w = (const float*)d_in[6];   // [64][128]
    const float* t2_b = (const float*)d_in[7];
    const float* yw   = (const float*)d_in[8];
    const float* nw   = (const float*)d_in[9];
    const int* src    = (const int*)d_in[10];
    const int* dst    = (const int*)d_in[11];
    const int* yn     = (const int*)d_in[12];
    float* outp = (float*)d_out;

    char* ws = (char*)d_ws;
    size_t off = 0;
    auto alloc = [&](size_t bytes) {
        void* p = ws + off;
        off = (off + bytes + 255) & ~(size_t)255;
        return p;
    };
    unsigned short* xb0 = (unsigned short*)alloc((size_t)N_NODES * HID * 2);
    unsigned short* xb1 = (unsigned short*)alloc((size_t)N_NODES * HID * 2);
    unsigned short* xb2 = (unsigned short*)alloc((size_t)N_NODES * HID * 2);
    unsigned short* wb  = (unsigned short*)alloc((size_t)8192 * 8 * 2);
    float* gd0    = (float*)alloc((size_t)N_NODES * 4);
    float* gs0    = (float*)alloc((size_t)N_NODES * 4);
    float* gd1    = (float*)alloc((size_t)N_NODES * 4);
    float* gs1    = (float*)alloc((size_t)N_NODES * 4);
    int*   deg    = (int*)alloc((size_t)N_NODES * 4);
    int*   rowptr = (int*)alloc((size_t)(N_NODES + 1) * 4);
    int*   cursor = (int*)alloc((size_t)N_NODES * 4);
    int*   csr    = (int*)alloc((size_t)N_EDGES * 4);
    int*   partials = (int*)alloc(64 * 4);
    int*   bofs     = (int*)alloc(64 * 4);
    (void)ws_size; (void)n_in; (void)in_sizes; (void)out_size;

    // CSR build (parallel scan: 49-block partials -> 1-wave scan -> 49-block write)
    hipMemsetAsync(deg, 0, (size_t)N_NODES * 4, stream);
    hist_k<<<(N_EDGES + 255) / 256, 256, 0, stream>>>(dst, deg);
    partial_k<<<SCAN_BLOCKS, 256, 0, stream>>>(deg, partials);
    scanp_k<<<1, 64, 0, stream>>>(partials, bofs, rowptr);
    scanw_k<<<SCAN_BLOCKS, 256, 0, stream>>>(deg, bofs, rowptr, cursor);
    fill_k<<<(N_EDGES + 255) / 256, 256, 0, stream>>>(src, dst, yn, cursor, csr);

    // W pack (tiny) + t1 with fused layer-0 gate (global_load_lds staged)
    wb_k<<<32, 256, 0, stream>>>(t1_w, wb);
    t1_k<<<N_NODES / 16, 256, 0, stream>>>(h, wb, t1_b, gw, xb0, gd0, gs0);

    int wave_blocks = (N_NODES * 64 + 255) / 256;   // one wave per node

    // layer 0: gather xb0, residual xb0 -> xb1, fused layer-1 gate dots
    agg_k<<<wave_blocks, 256, 0, stream>>>(xb0, xb0, rowptr, csr, d, gd0, gs0, gb, 0,
                                           yw, nw, gw + 256, gd1, gs1, xb1);
    // layer 1: gather xb1, residual xb0 (raw is FIXED across layers) -> xb2
    agg_k<<<wave_blocks, 256, 0, stream>>>(xb1, xb0, rowptr, csr, d, gd1, gs1, gb, 1,
                                           yw, nw, (const float*)nullptr,
                                           (float*)nullptr, (float*)nullptr, xb2);

    // t2 + log_softmax (bf16 x)
    out_k<<<(N_NODES + 63) / 64, 256, 0, stream>>>(xb2, t2_w, t2_b, outp);
}